// Round 13
// baseline (161.308 us; speedup 1.0000x reference)
//
#include <hip/hip_runtime.h>

typedef unsigned short u16;
typedef unsigned int   u32;
typedef unsigned long long u64;
typedef short bf16x8 __attribute__((ext_vector_type(8)));
typedef float f32x4  __attribute__((ext_vector_type(4)));

#define MFMA(a,b,c) __builtin_amdgcn_mfma_f32_16x16x32_bf16((a),(b),(c),0,0,0)

#if __has_builtin(__builtin_amdgcn_exp2f)
#define EXP2F(x) __builtin_amdgcn_exp2f(x)
#else
#define EXP2F(x) exp2f(x)
#endif
#if __has_builtin(__builtin_amdgcn_rcpf)
#define RCPF(x) __builtin_amdgcn_rcpf(x)
#else
#define RCPF(x) (1.0f/(x))
#endif

__device__ __forceinline__ u32 cvt_pk(float lo, float hi) {
  u32 r;
  asm("v_cvt_pk_bf16_f32 %0, %1, %2" : "=v"(r) : "v"(lo), "v"(hi));
  return r;
}
union FragU { u32 u[4]; bf16x8 v; };
__device__ __forceinline__ bf16x8 frag2(u32 a, u32 b) {
  FragU x; x.u[0] = a; x.u[1] = b; x.u[2] = 0; x.u[3] = 0; return x.v;
}
__device__ __forceinline__ bf16x8 frag4(u32 a, u32 b, u32 c, u32 d) {
  FragU x; x.u[0] = a; x.u[1] = b; x.u[2] = c; x.u[3] = d; return x.v;
}
__device__ __forceinline__ bf16x8 wfrag(const float* p) {
  f32x4 w0 = *(const f32x4*)p;
  f32x4 w1 = *(const f32x4*)(p + 4);
  return frag4(cvt_pk(w0[0], w0[1]), cvt_pk(w0[2], w0[3]),
               cvt_pk(w1[0], w1[1]), cvt_pk(w1[2], w1[3]));
}

// ---------------- LDS layout (bytes) ----------------
// Region B [0, 18432):      xpatch [144][64ch] swz (ph0-1) -> K [144][64ch] swz (ph2)
// Region A [18432, 39936):  V [64 ch][168 kpv-cols] bf16, stride 336 B
// Region C [39936, 48128):  ATT [64 q][64 ch] bf16 swz (dedicated -> no K-drain barrier)
// 48128 x 3 blocks = 144384 <= 163840 -> still 3 blocks/CU at waves_per_eu=6
constexpr int V_OFF   = 18432;
constexpr int ATT_OFF = 39936;
constexpr int SMEM_BYTES = 48128;

constexpr float SC_LOG2E = 0.36067376022224085f;  // 0.25 * log2(e)

// Bias in S^T fragment order: frag f = (h*4 + qt)*9 + tk; lane l; f32x4 over r.
__global__ __launch_bounds__(256)
void bias_expand(const float* __restrict__ rpb, float* __restrict__ bexp)
{
  int gid = blockIdx.x * 256 + threadIdx.x;      // < 9216
  int frag = gid >> 6, l = gid & 63;
  int hh = frag / 36, rem = frag % 36, qt = rem / 9, tk = rem % 9;
  int l15 = l & 15, lg = l >> 4;
  int q = qt * 16 + l15;
  int qy = q >> 3, qx = q & 7;
  f32x4 v;
#pragma unroll
  for (int r = 0; r < 4; ++r) {
    int p = tk * 16 + lg * 4 + r;
    int ky = p / 12, kx = p - ky * 12;
    int idx = (ky - qy + 7) * 19 + (kx - qx + 7);
    v[r] = rpb[idx * 4 + hh] * 1.4426950408889634f;
  }
  *(f32x4*)(bexp + (size_t)gid * 4) = v;
}

__global__ __launch_bounds__(512, 6)
void fused_win_attn(const float* __restrict__ x, const float* __restrict__ qkv_w,
                    const float* __restrict__ qkv_b, const float* __restrict__ proj_w,
                    const float* __restrict__ proj_b, const float* __restrict__ bexp,
                    float* __restrict__ out)
{
  __shared__ __align__(16) char Sm[SMEM_BYTES];
  const int tid = threadIdx.x;
  const int l   = tid & 63;
  const int wv  = tid >> 6;        // wave 0..7
  const int l15 = l & 15;
  const int lg  = l >> 4;          // 0..3
  const int h   = wv >> 1, qh = wv & 1;

  // XCD-aware bijective swizzle (4096 % 8 == 0)
  int bid = blockIdx.x;
  int win = (bid & 7) * 512 + (bid >> 3);
  const int bb = win >> 10;
  const int wl = win & 1023;
  const int oy = (wl >> 5) * 8, ox = (wl & 31) * 8;
  const int py0 = oy - 2, px0 = ox - 2;

  // ---- Phase 0: zero V kpv-pad gaps, stage x patch (bf16, swz, region B) ----
  {
    int ch = tid >> 3, j = tid & 7;
    *(u64*)(Sm + V_OFF + ch * 336 + 256 + j * 8) = 0ull;
  }
  {
    const float* xb = x + (size_t)bb * 64 * 65536;
    int pix = tid % 144;
    int cq  = tid / 144;
#pragma unroll
    for (int it = 0; it < 5; ++it) {
      if (it < 4 || tid < 256) { // total 2304 units = 144 pix * 16 ch-quads
        int prow = (pix * 171) >> 11;
        int pcol = pix - prow * 12;
        int gy = py0 + prow, gx = px0 + pcol;
        float v0 = 0.f, v1 = 0.f, v2 = 0.f, v3 = 0.f;
        if (((u32)gy < 256u) & ((u32)gx < 256u)) {
          const float* p = xb + (size_t)(cq * 4) * 65536 + gy * 256 + gx;
          v0 = p[0]; v1 = p[65536]; v2 = p[131072]; v3 = p[196608];
        }
        u64 pk = (u64)cvt_pk(v0, v1) | ((u64)cvt_pk(v2, v3) << 32);
        *(u64*)(Sm + ((pix * 128 + cq * 8) ^ ((pix & 7) << 4))) = pk;
      }
      pix += 80; int wr = (pix >= 144); pix -= wr ? 144 : 0; cq += 3 + wr;
    }
  }
  __syncthreads();   // B1: xpatch visible

  // ---- Phase 1: QKV GEMMs into REGISTERS (K and V), Q in-reg ----
  u64 kv[9];
  if (wv < 4) {
    // K channels tile wv: D[m=ch, n=pix]
    const float* wr_ = qkv_w + (size_t)(64 + wv * 16 + l15) * 64;
    bf16x8 a0 = wfrag(wr_ + lg * 8), a1 = wfrag(wr_ + 32 + lg * 8);
    float kb[4];
#pragma unroll
    for (int r = 0; r < 4; ++r) kb[r] = qkv_b[64 + wv * 16 + lg * 4 + r];
#pragma unroll
    for (int nt = 0; nt < 9; ++nt) {
      int pix = nt * 16 + l15;
      int swz = (pix & 7) << 4;
      bf16x8 b0 = *(const bf16x8*)(Sm + ((pix * 128 + lg * 16) ^ swz));
      bf16x8 b1 = *(const bf16x8*)(Sm + ((pix * 128 + 64 + lg * 16) ^ swz));
      f32x4 acc = {0.f, 0.f, 0.f, 0.f};
      acc = MFMA(a0, b0, acc);
      acc = MFMA(a1, b1, acc);
      kv[nt] = (u64)cvt_pk(acc[0] + kb[0], acc[1] + kb[1]) |
               ((u64)cvt_pk(acc[2] + kb[2], acc[3] + kb[3]) << 32);
    }
  } else {
    // V channels tile vt: orientation-2 D[m=pix, n=ch], kpv col packing
    int vt = wv - 4;
    const float* wr_ = qkv_w + (size_t)(128 + vt * 16 + l15) * 64;
    bf16x8 bw0 = wfrag(wr_ + lg * 8), bw1 = wfrag(wr_ + 32 + lg * 8);
    float vb = qkv_b[128 + vt * 16 + l15];
#pragma unroll
    for (int nt = 0; nt < 9; ++nt) {
      int pr = nt * 16 + l15;
      int swz = (pr & 7) << 4;
      bf16x8 a0 = *(const bf16x8*)(Sm + ((pr * 128 + lg * 16) ^ swz));
      bf16x8 a1 = *(const bf16x8*)(Sm + ((pr * 128 + 64 + lg * 16) ^ swz));
      f32x4 acc = {0.f, 0.f, 0.f, 0.f};
      acc = MFMA(a0, bw0, acc);
      acc = MFMA(a1, bw1, acc);
      kv[nt] = (u64)cvt_pk(acc[0] + vb, acc[1] + vb) |
               ((u64)cvt_pk(acc[2] + vb, acc[3] + vb) << 32);
    }
  }
  // Q for this wave's own (h, qh), kept in-reg
  u32 qf[2][2];
  {
    const float* wq = qkv_w + (size_t)(h * 16 + l15) * 64;
    bf16x8 qa0 = wfrag(wq + lg * 8), qa1 = wfrag(wq + 32 + lg * 8);
    float qsb[4];
#pragma unroll
    for (int r = 0; r < 4; ++r) qsb[r] = qkv_b[h * 16 + lg * 4 + r] * SC_LOG2E;
#pragma unroll
    for (int t = 0; t < 2; ++t) {
      int q = (qh * 2 + t) * 16 + l15;
      int pix = ((q >> 3) + 2) * 12 + (q & 7) + 2;
      int swz = (pix & 7) << 4;
      bf16x8 b0 = *(const bf16x8*)(Sm + ((pix * 128 + lg * 16) ^ swz));
      bf16x8 b1 = *(const bf16x8*)(Sm + ((pix * 128 + 64 + lg * 16) ^ swz));
      f32x4 acc = {0.f, 0.f, 0.f, 0.f};
      acc = MFMA(qa0, b0, acc);
      acc = MFMA(qa1, b1, acc);
      qf[t][0] = cvt_pk(acc[0] * SC_LOG2E + qsb[0], acc[1] * SC_LOG2E + qsb[1]);
      qf[t][1] = cvt_pk(acc[2] * SC_LOG2E + qsb[2], acc[3] * SC_LOG2E + qsb[3]);
    }
  }
  __syncthreads();   // B2: all xpatch reads done

  // ---- Phase 1b: spill K/V regs to LDS (K overwrites xpatch region) ----
  if (wv < 4) {
#pragma unroll
    for (int nt = 0; nt < 9; ++nt) {
      int pix = nt * 16 + l15;
      *(u64*)(Sm + ((pix * 128 + wv * 32 + lg * 8) ^ ((pix & 7) << 4))) = kv[nt];
    }
  } else {
    int vt = wv - 4;
#pragma unroll
    for (int nt = 0; nt < 9; ++nt) {
      int colb = (nt >> 1) * 64 + lg * 16 + (nt & 1) * 8;
      *(u64*)(Sm + V_OFF + (vt * 16 + l15) * 336 + colb) = kv[nt];
    }
  }
  __syncthreads();   // B3: K, V visible

  // ---- Hoisted phase-4 weights: load/convert during attention phase ----
  const int mt4 = wv & 3;
  const int nb4 = (wv >> 2) * 2;
  bf16x8 pjb0, pjb1, pjb2, pjb3;
  float pb4_0, pb4_1;
  {
    const float* pw0 = proj_w + (size_t)((nb4 + 0) * 16 + l15) * 64;
    const float* pw1 = proj_w + (size_t)((nb4 + 1) * 16 + l15) * 64;
    pjb0 = wfrag(pw0 + lg * 8); pjb1 = wfrag(pw0 + 32 + lg * 8);
    pjb2 = wfrag(pw1 + lg * 8); pjb3 = wfrag(pw1 + 32 + lg * 8);
    pb4_0 = proj_b[(nb4 + 0) * 16 + l15];
    pb4_1 = proj_b[(nb4 + 1) * 16 + l15];
  }

  // ---- Phase 2+3: BOTH q-halves fused — shared K/V fragment loads,
  //      two independent MFMA/exp2 chains. No max-sub (range-safe).
  //      ATT written to dedicated region C -> no drain barrier needed. ----
  const int kcol = h * 32 + lg * 8;
  {
    const bf16x8 bq0 = frag2(qf[0][0], qf[0][1]);
    const bf16x8 bq1 = frag2(qf[1][0], qf[1][1]);
    const float* bp0 = bexp + ((size_t)((h * 4 + qh * 2 + 0) * 9) * 64 + l) * 4;
    const float* bp1 = bexp + ((size_t)((h * 4 + qh * 2 + 1) * 9) * 64 + l) * 4;
    u32 pk0[9][2], pk1[9][2];
    f32x4 sum40 = {0.f, 0.f, 0.f, 0.f}, sum41 = {0.f, 0.f, 0.f, 0.f};
    __builtin_amdgcn_s_setprio(1);
#pragma unroll
    for (int tk = 0; tk < 9; ++tk) {
      int p = tk * 16 + l15;
      u64 kk = *(const u64*)(Sm + ((p * 128 + kcol) ^ ((p & 7) << 4)));
      bf16x8 ak = frag2((u32)kk, (u32)(kk >> 32));
      f32x4 z = {0.f, 0.f, 0.f, 0.f};
      f32x4 s0 = MFMA(ak, bq0, z);
      f32x4 s1 = MFMA(ak, bq1, z);
      s0 += *(const f32x4*)(bp0 + tk * 256);
      s1 += *(const f32x4*)(bp1 + tk * 256);
      f32x4 e0, e1;
#pragma unroll
      for (int r = 0; r < 4; ++r) { e0[r] = EXP2F(s0[r]); e1[r] = EXP2F(s1[r]); }
      sum40 += e0; sum41 += e1;
      pk0[tk][0] = cvt_pk(e0[0], e0[1]); pk0[tk][1] = cvt_pk(e0[2], e0[3]);
      pk1[tk][0] = cvt_pk(e1[0], e1[1]); pk1[tk][1] = cvt_pk(e1[2], e1[3]);
    }
    __builtin_amdgcn_s_setprio(0);
    float sum0 = (sum40[0] + sum40[1]) + (sum40[2] + sum40[3]);
    float sum1 = (sum41[0] + sum41[1]) + (sum41[2] + sum41[3]);
    sum0 += __shfl_xor(sum0, 16); sum1 += __shfl_xor(sum1, 16);
    sum0 += __shfl_xor(sum0, 32); sum1 += __shfl_xor(sum1, 32);
    float rs0 = RCPF(sum0), rs1 = RCPF(sum1);
    f32x4 o0 = {0.f, 0.f, 0.f, 0.f}, o1 = {0.f, 0.f, 0.f, 0.f};
    __builtin_amdgcn_s_setprio(1);
#pragma unroll
    for (int s5 = 0; s5 < 5; ++s5) {
      bf16x8 av = *(const bf16x8*)(Sm + V_OFF + (h * 16 + l15) * 336 + s5 * 64 + lg * 16);
      bf16x8 bpa = (s5 < 4) ? frag4(pk0[2*s5][0], pk0[2*s5][1], pk0[2*s5+1][0], pk0[2*s5+1][1])
                            : frag2(pk0[8][0], pk0[8][1]);
      bf16x8 bpb = (s5 < 4) ? frag4(pk1[2*s5][0], pk1[2*s5][1], pk1[2*s5+1][0], pk1[2*s5+1][1])
                            : frag2(pk1[8][0], pk1[8][1]);
      o0 = MFMA(av, bpa, o0);
      o1 = MFMA(av, bpb, o1);
    }
    __builtin_amdgcn_s_setprio(0);
    // write ATT (region C, no alias with K) immediately
    {
      int q0 = (qh * 2 + 0) * 16 + l15;
      u64 w0 = (u64)cvt_pk(o0[0] * rs0, o0[1] * rs0) |
               ((u64)cvt_pk(o0[2] * rs0, o0[3] * rs0) << 32);
      *(u64*)(Sm + ATT_OFF + ((q0 * 128 + kcol) ^ ((q0 & 7) << 4))) = w0;
      int q1 = (qh * 2 + 1) * 16 + l15;
      u64 w1 = (u64)cvt_pk(o1[0] * rs1, o1[1] * rs1) |
               ((u64)cvt_pk(o1[2] * rs1, o1[3] * rs1) << 32);
      *(u64*)(Sm + ATT_OFF + ((q1 * 128 + kcol) ^ ((q1 & 7) << 4))) = w1;
    }
  }
  __syncthreads();   // B4: ATT visible

  // ---- Phase 4: projection, orientation-2: D[m=q, n=och], f32x4 stores ----
  {
    int q = mt4 * 16 + l15, swz = (q & 7) << 4;
    bf16x8 aa0 = *(const bf16x8*)(Sm + ATT_OFF + ((q * 128 + lg * 16) ^ swz));
    bf16x8 aa1 = *(const bf16x8*)(Sm + ATT_OFF + ((q * 128 + 64 + lg * 16) ^ swz));
    int qrow = mt4 * 16 + lg * 4;
    int gy = oy + (qrow >> 3), gx = ox + (qrow & 7);
    {
      f32x4 acc = {0.f, 0.f, 0.f, 0.f};
      acc = MFMA(aa0, pjb0, acc);
      acc = MFMA(aa1, pjb1, acc);
      f32x4 st = {acc[0] + pb4_0, acc[1] + pb4_0, acc[2] + pb4_0, acc[3] + pb4_0};
      float* yp = out + (((size_t)bb * 64 + (nb4 + 0) * 16 + l15) * 256 + gy) * 256 + gx;
      *(f32x4*)yp = st;
    }
    {
      f32x4 acc = {0.f, 0.f, 0.f, 0.f};
      acc = MFMA(aa0, pjb2, acc);
      acc = MFMA(aa1, pjb3, acc);
      f32x4 st = {acc[0] + pb4_1, acc[1] + pb4_1, acc[2] + pb4_1, acc[3] + pb4_1};
      float* yp = out + (((size_t)bb * 64 + (nb4 + 1) * 16 + l15) * 256 + gy) * 256 + gx;
      *(f32x4*)yp = st;
    }
  }
}

extern "C" void kernel_launch(void* const* d_in, const int* in_sizes, int n_in,
                              void* d_out, int out_size, void* d_ws, size_t ws_size,
                              hipStream_t stream) {
  const float* x      = (const float*)d_in[0];
  const float* qkv_w  = (const float*)d_in[1];
  const float* qkv_b  = (const float*)d_in[2];
  const float* rpb    = (const float*)d_in[3];
  const float* proj_w = (const float*)d_in[4];
  const float* proj_b = (const float*)d_in[5];
  float* out  = (float*)d_out;
  float* bexp = (float*)d_ws;   // 147456 bytes

  bias_expand<<<36, 256, 0, stream>>>(rpb, bexp);
  fused_win_attn<<<4096, 512, 0, stream>>>(x, qkv_w, qkv_b, proj_w, proj_b, bexp, out);
}

// Round 14
// 119.230 us; speedup vs baseline: 1.3529x; 1.3529x over previous
//
#include <hip/hip_runtime.h>

typedef unsigned short u16;
typedef unsigned int   u32;
typedef unsigned long long u64;
typedef short bf16x8 __attribute__((ext_vector_type(8)));
typedef float f32x4  __attribute__((ext_vector_type(4)));

#define MFMA(a,b,c) __builtin_amdgcn_mfma_f32_16x16x32_bf16((a),(b),(c),0,0,0)

#if __has_builtin(__builtin_amdgcn_exp2f)
#define EXP2F(x) __builtin_amdgcn_exp2f(x)
#else
#define EXP2F(x) exp2f(x)
#endif
#if __has_builtin(__builtin_amdgcn_rcpf)
#define RCPF(x) __builtin_amdgcn_rcpf(x)
#else
#define RCPF(x) (1.0f/(x))
#endif

__device__ __forceinline__ u32 cvt_pk(float lo, float hi) {
  u32 r;
  asm("v_cvt_pk_bf16_f32 %0, %1, %2" : "=v"(r) : "v"(lo), "v"(hi));
  return r;
}
union FragU { u32 u[4]; bf16x8 v; };
__device__ __forceinline__ bf16x8 frag2(u32 a, u32 b) {
  FragU x; x.u[0] = a; x.u[1] = b; x.u[2] = 0; x.u[3] = 0; return x.v;
}
__device__ __forceinline__ bf16x8 frag4(u32 a, u32 b, u32 c, u32 d) {
  FragU x; x.u[0] = a; x.u[1] = b; x.u[2] = c; x.u[3] = d; return x.v;
}
__device__ __forceinline__ bf16x8 wfrag(const float* p) {
  f32x4 w0 = *(const f32x4*)p;
  f32x4 w1 = *(const f32x4*)(p + 4);
  return frag4(cvt_pk(w0[0], w0[1]), cvt_pk(w0[2], w0[3]),
               cvt_pk(w1[0], w1[1]), cvt_pk(w1[2], w1[3]));
}

// ---------------- LDS layout (bytes) ----------------
// Region B [0, 18432):      xpatch [144][64ch] swz (ph0-1) -> K [144][64ch] swz (ph2)
// Region A [18432, 39936):  V [64 ch][168 kpv-cols] bf16, stride 336 B
// Region C [39936, 48128):  ATT [64 q][64 ch] bf16 swz (dedicated -> no K-drain barrier)
// 48128 x 3 blocks = 144384 <= 163840 -> 3 blocks/CU at waves_per_eu=6
constexpr int V_OFF   = 18432;
constexpr int ATT_OFF = 39936;
constexpr int SMEM_BYTES = 48128;

constexpr float SC_LOG2E = 0.36067376022224085f;  // 0.25 * log2(e)

// Bias in S^T fragment order: frag f = (h*4 + qt)*9 + tk; lane l; f32x4 over r.
__global__ __launch_bounds__(256)
void bias_expand(const float* __restrict__ rpb, float* __restrict__ bexp)
{
  int gid = blockIdx.x * 256 + threadIdx.x;      // < 9216
  int frag = gid >> 6, l = gid & 63;
  int hh = frag / 36, rem = frag % 36, qt = rem / 9, tk = rem % 9;
  int l15 = l & 15, lg = l >> 4;
  int q = qt * 16 + l15;
  int qy = q >> 3, qx = q & 7;
  f32x4 v;
#pragma unroll
  for (int r = 0; r < 4; ++r) {
    int p = tk * 16 + lg * 4 + r;
    int ky = p / 12, kx = p - ky * 12;
    int idx = (ky - qy + 7) * 19 + (kx - qx + 7);
    v[r] = rpb[idx * 4 + hh] * 1.4426950408889634f;
  }
  *(f32x4*)(bexp + (size_t)gid * 4) = v;
}

__global__ __launch_bounds__(512, 6)
void fused_win_attn(const float* __restrict__ x, const float* __restrict__ qkv_w,
                    const float* __restrict__ qkv_b, const float* __restrict__ proj_w,
                    const float* __restrict__ proj_b, const float* __restrict__ bexp,
                    float* __restrict__ out)
{
  __shared__ __align__(16) char Sm[SMEM_BYTES];
  const int tid = threadIdx.x;
  const int l   = tid & 63;
  const int wv  = tid >> 6;        // wave 0..7
  const int l15 = l & 15;
  const int lg  = l >> 4;          // 0..3
  const int h   = wv >> 1, qh = wv & 1;

  // XCD-aware bijective swizzle (4096 % 8 == 0)
  int bid = blockIdx.x;
  int win = (bid & 7) * 512 + (bid >> 3);
  const int bb = win >> 10;
  const int wl = win & 1023;
  const int oy = (wl >> 5) * 8, ox = (wl & 31) * 8;
  const int py0 = oy - 2, px0 = ox - 2;

  // ---- Phase 0: zero V kpv-pad gaps, stage x patch (bf16, swz, region B) ----
  {
    int ch = tid >> 3, j = tid & 7;
    *(u64*)(Sm + V_OFF + ch * 336 + 256 + j * 8) = 0ull;
  }
  {
    const float* xb = x + (size_t)bb * 64 * 65536;
    int pix = tid % 144;
    int cq  = tid / 144;
#pragma unroll
    for (int it = 0; it < 5; ++it) {
      if (it < 4 || tid < 256) { // total 2304 units = 144 pix * 16 ch-quads
        int prow = (pix * 171) >> 11;
        int pcol = pix - prow * 12;
        int gy = py0 + prow, gx = px0 + pcol;
        float v0 = 0.f, v1 = 0.f, v2 = 0.f, v3 = 0.f;
        if (((u32)gy < 256u) & ((u32)gx < 256u)) {
          const float* p = xb + (size_t)(cq * 4) * 65536 + gy * 256 + gx;
          v0 = p[0]; v1 = p[65536]; v2 = p[131072]; v3 = p[196608];
        }
        u64 pk = (u64)cvt_pk(v0, v1) | ((u64)cvt_pk(v2, v3) << 32);
        *(u64*)(Sm + ((pix * 128 + cq * 8) ^ ((pix & 7) << 4))) = pk;
      }
      pix += 80; int wr = (pix >= 144); pix -= wr ? 144 : 0; cq += 3 + wr;
    }
  }
  __syncthreads();   // B1: xpatch visible

  // ---- Phase 1: QKV GEMMs into REGISTERS (K and V), Q in-reg ----
  u64 kv[9];
  if (wv < 4) {
    // K channels tile wv: D[m=ch, n=pix]
    const float* wr_ = qkv_w + (size_t)(64 + wv * 16 + l15) * 64;
    bf16x8 a0 = wfrag(wr_ + lg * 8), a1 = wfrag(wr_ + 32 + lg * 8);
    float kb[4];
#pragma unroll
    for (int r = 0; r < 4; ++r) kb[r] = qkv_b[64 + wv * 16 + lg * 4 + r];
#pragma unroll
    for (int nt = 0; nt < 9; ++nt) {
      int pix = nt * 16 + l15;
      int swz = (pix & 7) << 4;
      bf16x8 b0 = *(const bf16x8*)(Sm + ((pix * 128 + lg * 16) ^ swz));
      bf16x8 b1 = *(const bf16x8*)(Sm + ((pix * 128 + 64 + lg * 16) ^ swz));
      f32x4 acc = {0.f, 0.f, 0.f, 0.f};
      acc = MFMA(a0, b0, acc);
      acc = MFMA(a1, b1, acc);
      kv[nt] = (u64)cvt_pk(acc[0] + kb[0], acc[1] + kb[1]) |
               ((u64)cvt_pk(acc[2] + kb[2], acc[3] + kb[3]) << 32);
    }
  } else {
    // V channels tile vt: orientation-2 D[m=pix, n=ch], kpv col packing
    int vt = wv - 4;
    const float* wr_ = qkv_w + (size_t)(128 + vt * 16 + l15) * 64;
    bf16x8 bw0 = wfrag(wr_ + lg * 8), bw1 = wfrag(wr_ + 32 + lg * 8);
    float vb = qkv_b[128 + vt * 16 + l15];
#pragma unroll
    for (int nt = 0; nt < 9; ++nt) {
      int pr = nt * 16 + l15;
      int swz = (pr & 7) << 4;
      bf16x8 a0 = *(const bf16x8*)(Sm + ((pr * 128 + lg * 16) ^ swz));
      bf16x8 a1 = *(const bf16x8*)(Sm + ((pr * 128 + 64 + lg * 16) ^ swz));
      f32x4 acc = {0.f, 0.f, 0.f, 0.f};
      acc = MFMA(a0, bw0, acc);
      acc = MFMA(a1, bw1, acc);
      kv[nt] = (u64)cvt_pk(acc[0] + vb, acc[1] + vb) |
               ((u64)cvt_pk(acc[2] + vb, acc[3] + vb) << 32);
    }
  }
  // Q for this wave's own (h, qh), kept in-reg
  u32 qf[2][2];
  {
    const float* wq = qkv_w + (size_t)(h * 16 + l15) * 64;
    bf16x8 qa0 = wfrag(wq + lg * 8), qa1 = wfrag(wq + 32 + lg * 8);
    float qsb[4];
#pragma unroll
    for (int r = 0; r < 4; ++r) qsb[r] = qkv_b[h * 16 + lg * 4 + r] * SC_LOG2E;
#pragma unroll
    for (int t = 0; t < 2; ++t) {
      int q = (qh * 2 + t) * 16 + l15;
      int pix = ((q >> 3) + 2) * 12 + (q & 7) + 2;
      int swz = (pix & 7) << 4;
      bf16x8 b0 = *(const bf16x8*)(Sm + ((pix * 128 + lg * 16) ^ swz));
      bf16x8 b1 = *(const bf16x8*)(Sm + ((pix * 128 + 64 + lg * 16) ^ swz));
      f32x4 acc = {0.f, 0.f, 0.f, 0.f};
      acc = MFMA(qa0, b0, acc);
      acc = MFMA(qa1, b1, acc);
      qf[t][0] = cvt_pk(acc[0] * SC_LOG2E + qsb[0], acc[1] * SC_LOG2E + qsb[1]);
      qf[t][1] = cvt_pk(acc[2] * SC_LOG2E + qsb[2], acc[3] * SC_LOG2E + qsb[3]);
    }
  }
  __syncthreads();   // B2: all xpatch reads done

  // ---- Phase 1b: spill K/V regs to LDS (K overwrites xpatch region) ----
  if (wv < 4) {
#pragma unroll
    for (int nt = 0; nt < 9; ++nt) {
      int pix = nt * 16 + l15;
      *(u64*)(Sm + ((pix * 128 + wv * 32 + lg * 8) ^ ((pix & 7) << 4))) = kv[nt];
    }
  } else {
    int vt = wv - 4;
#pragma unroll
    for (int nt = 0; nt < 9; ++nt) {
      int colb = (nt >> 1) * 64 + lg * 16 + (nt & 1) * 8;
      *(u64*)(Sm + V_OFF + (vt * 16 + l15) * 336 + colb) = kv[nt];
    }
  }
  __syncthreads();   // B3: K, V visible

  // ---- Phase 2+3: BOTH q-halves fused — shared K/V fragment loads,
  //      two independent MFMA/exp2 chains. No max-sub (range-safe).
  //      ATT -> dedicated region C immediately (no K-drain barrier). ----
  const int kcol = h * 32 + lg * 8;
  {
    const bf16x8 bq0 = frag2(qf[0][0], qf[0][1]);
    const bf16x8 bq1 = frag2(qf[1][0], qf[1][1]);
    const float* bp0 = bexp + ((size_t)((h * 4 + qh * 2 + 0) * 9) * 64 + l) * 4;
    const float* bp1 = bexp + ((size_t)((h * 4 + qh * 2 + 1) * 9) * 64 + l) * 4;
    u32 pk0[9][2], pk1[9][2];
    f32x4 sum40 = {0.f, 0.f, 0.f, 0.f}, sum41 = {0.f, 0.f, 0.f, 0.f};
    __builtin_amdgcn_s_setprio(1);
#pragma unroll
    for (int tk = 0; tk < 9; ++tk) {
      int p = tk * 16 + l15;
      u64 kk = *(const u64*)(Sm + ((p * 128 + kcol) ^ ((p & 7) << 4)));
      bf16x8 ak = frag2((u32)kk, (u32)(kk >> 32));
      f32x4 z = {0.f, 0.f, 0.f, 0.f};
      f32x4 s0 = MFMA(ak, bq0, z);
      f32x4 s1 = MFMA(ak, bq1, z);
      s0 += *(const f32x4*)(bp0 + tk * 256);
      s1 += *(const f32x4*)(bp1 + tk * 256);
      f32x4 e0, e1;
#pragma unroll
      for (int r = 0; r < 4; ++r) { e0[r] = EXP2F(s0[r]); e1[r] = EXP2F(s1[r]); }
      sum40 += e0; sum41 += e1;
      pk0[tk][0] = cvt_pk(e0[0], e0[1]); pk0[tk][1] = cvt_pk(e0[2], e0[3]);
      pk1[tk][0] = cvt_pk(e1[0], e1[1]); pk1[tk][1] = cvt_pk(e1[2], e1[3]);
    }
    __builtin_amdgcn_s_setprio(0);
    float sum0 = (sum40[0] + sum40[1]) + (sum40[2] + sum40[3]);
    float sum1 = (sum41[0] + sum41[1]) + (sum41[2] + sum41[3]);
    sum0 += __shfl_xor(sum0, 16); sum1 += __shfl_xor(sum1, 16);
    sum0 += __shfl_xor(sum0, 32); sum1 += __shfl_xor(sum1, 32);
    float rs0 = RCPF(sum0), rs1 = RCPF(sum1);
    f32x4 o0 = {0.f, 0.f, 0.f, 0.f}, o1 = {0.f, 0.f, 0.f, 0.f};
    __builtin_amdgcn_s_setprio(1);
#pragma unroll
    for (int s5 = 0; s5 < 5; ++s5) {
      bf16x8 av = *(const bf16x8*)(Sm + V_OFF + (h * 16 + l15) * 336 + s5 * 64 + lg * 16);
      bf16x8 bpa = (s5 < 4) ? frag4(pk0[2*s5][0], pk0[2*s5][1], pk0[2*s5+1][0], pk0[2*s5+1][1])
                            : frag2(pk0[8][0], pk0[8][1]);
      bf16x8 bpb = (s5 < 4) ? frag4(pk1[2*s5][0], pk1[2*s5][1], pk1[2*s5+1][0], pk1[2*s5+1][1])
                            : frag2(pk1[8][0], pk1[8][1]);
      o0 = MFMA(av, bpa, o0);
      o1 = MFMA(av, bpb, o1);
    }
    __builtin_amdgcn_s_setprio(0);
    // write ATT (region C, no alias with K) immediately
    {
      int q0 = (qh * 2 + 0) * 16 + l15;
      u64 w0 = (u64)cvt_pk(o0[0] * rs0, o0[1] * rs0) |
               ((u64)cvt_pk(o0[2] * rs0, o0[3] * rs0) << 32);
      *(u64*)(Sm + ATT_OFF + ((q0 * 128 + kcol) ^ ((q0 & 7) << 4))) = w0;
      int q1 = (qh * 2 + 1) * 16 + l15;
      u64 w1 = (u64)cvt_pk(o1[0] * rs1, o1[1] * rs1) |
               ((u64)cvt_pk(o1[2] * rs1, o1[3] * rs1) << 32);
      *(u64*)(Sm + ATT_OFF + ((q1 * 128 + kcol) ^ ((q1 & 7) << 4))) = w1;
    }
  }
  __syncthreads();   // B4: ATT visible

  // ---- Phase 4: projection, orientation-2: D[m=q, n=och], f32x4 stores ----
  {
    int mt = wv & 3;
    int nb = (wv >> 2) * 2;
    int q = mt * 16 + l15, swz = (q & 7) << 4;
    bf16x8 aa0 = *(const bf16x8*)(Sm + ATT_OFF + ((q * 128 + lg * 16) ^ swz));
    bf16x8 aa1 = *(const bf16x8*)(Sm + ATT_OFF + ((q * 128 + 64 + lg * 16) ^ swz));
    int qrow = mt * 16 + lg * 4;
    int gy = oy + (qrow >> 3), gx = ox + (qrow & 7);
#pragma unroll
    for (int nn = 0; nn < 2; ++nn) {
      int ntile = nb + nn;
      const float* pw = proj_w + (size_t)(ntile * 16 + l15) * 64;
      bf16x8 b0 = wfrag(pw + lg * 8), b1 = wfrag(pw + 32 + lg * 8);
      f32x4 acc = {0.f, 0.f, 0.f, 0.f};
      acc = MFMA(aa0, b0, acc);
      acc = MFMA(aa1, b1, acc);
      float pb = proj_b[ntile * 16 + l15];
      f32x4 st = {acc[0] + pb, acc[1] + pb, acc[2] + pb, acc[3] + pb};
      float* yp = out + (((size_t)bb * 64 + ntile * 16 + l15) * 256 + gy) * 256 + gx;
      *(f32x4*)yp = st;
    }
  }
}

extern "C" void kernel_launch(void* const* d_in, const int* in_sizes, int n_in,
                              void* d_out, int out_size, void* d_ws, size_t ws_size,
                              hipStream_t stream) {
  const float* x      = (const float*)d_in[0];
  const float* qkv_w  = (const float*)d_in[1];
  const float* qkv_b  = (const float*)d_in[2];
  const float* rpb    = (const float*)d_in[3];
  const float* proj_w = (const float*)d_in[4];
  const float* proj_b = (const float*)d_in[5];
  float* out  = (float*)d_out;
  float* bexp = (float*)d_ws;   // 147456 bytes

  bias_expand<<<36, 256, 0, stream>>>(rpb, bexp);
  fused_win_attn<<<4096, 512, 0, stream>>>(x, qkv_w, qkv_b, proj_w, proj_b, bexp, out);
}

// Round 15
// 117.464 us; speedup vs baseline: 1.3733x; 1.0150x over previous
//
#include <hip/hip_runtime.h>

typedef unsigned short u16;
typedef unsigned int   u32;
typedef unsigned long long u64;
typedef short bf16x8 __attribute__((ext_vector_type(8)));
typedef float f32x4  __attribute__((ext_vector_type(4)));

#define MFMA(a,b,c) __builtin_amdgcn_mfma_f32_16x16x32_bf16((a),(b),(c),0,0,0)

#if __has_builtin(__builtin_amdgcn_exp2f)
#define EXP2F(x) __builtin_amdgcn_exp2f(x)
#else
#define EXP2F(x) exp2f(x)
#endif
#if __has_builtin(__builtin_amdgcn_rcpf)
#define RCPF(x) __builtin_amdgcn_rcpf(x)
#else
#define RCPF(x) (1.0f/(x))
#endif

__device__ __forceinline__ u32 cvt_pk(float lo, float hi) {
  u32 r;
  asm("v_cvt_pk_bf16_f32 %0, %1, %2" : "=v"(r) : "v"(lo), "v"(hi));
  return r;
}
union FragU { u32 u[4]; bf16x8 v; };
__device__ __forceinline__ bf16x8 frag2(u32 a, u32 b) {
  FragU x; x.u[0] = a; x.u[1] = b; x.u[2] = 0; x.u[3] = 0; return x.v;
}
__device__ __forceinline__ bf16x8 frag4(u32 a, u32 b, u32 c, u32 d) {
  FragU x; x.u[0] = a; x.u[1] = b; x.u[2] = c; x.u[3] = d; return x.v;
}
__device__ __forceinline__ bf16x8 wfrag(const float* p) {
  f32x4 w0 = *(const f32x4*)p;
  f32x4 w1 = *(const f32x4*)(p + 4);
  return frag4(cvt_pk(w0[0], w0[1]), cvt_pk(w0[2], w0[3]),
               cvt_pk(w1[0], w1[1]), cvt_pk(w1[2], w1[3]));
}

// ---------------- LDS layout (bytes) ----------------
// Region B [0, 18432): xpatch [144][64ch] swz (ph0-1) -> K [144][64ch] swz (ph2)
//                      -> ATT [64 q][64 ch] swz (ph3b-4)
// Region A [18432, 39936): V [64 ch][168 kpv-cols] bf16, stride 336 B
constexpr int V_OFF = 18432;
constexpr int SMEM_BYTES = 39936;

constexpr float SC_LOG2E = 0.36067376022224085f;  // 0.25 * log2(e)

// Bias in S^T fragment order: frag f = (h*4 + qt)*9 + tk; lane l; f32x4 over r.
__global__ __launch_bounds__(256)
void bias_expand(const float* __restrict__ rpb, float* __restrict__ bexp)
{
  int gid = blockIdx.x * 256 + threadIdx.x;      // < 9216
  int frag = gid >> 6, l = gid & 63;
  int hh = frag / 36, rem = frag % 36, qt = rem / 9, tk = rem % 9;
  int l15 = l & 15, lg = l >> 4;
  int q = qt * 16 + l15;
  int qy = q >> 3, qx = q & 7;
  f32x4 v;
#pragma unroll
  for (int r = 0; r < 4; ++r) {
    int p = tk * 16 + lg * 4 + r;
    int ky = p / 12, kx = p - ky * 12;
    int idx = (ky - qy + 7) * 19 + (kx - qx + 7);
    v[r] = rpb[idx * 4 + hh] * 1.4426950408889634f;
  }
  *(f32x4*)(bexp + (size_t)gid * 4) = v;
}

__global__ __launch_bounds__(512, 6)
void fused_win_attn(const float* __restrict__ x, const float* __restrict__ qkv_w,
                    const float* __restrict__ qkv_b, const float* __restrict__ proj_w,
                    const float* __restrict__ proj_b, const float* __restrict__ bexp,
                    float* __restrict__ out)
{
  __shared__ __align__(16) char Sm[SMEM_BYTES];
  const int tid = threadIdx.x;
  const int l   = tid & 63;
  const int wv  = tid >> 6;        // wave 0..7
  const int l15 = l & 15;
  const int lg  = l >> 4;          // 0..3
  const int h   = wv >> 1, qh = wv & 1;

  // XCD-aware bijective swizzle (4096 % 8 == 0)
  int bid = blockIdx.x;
  int win = (bid & 7) * 512 + (bid >> 3);
  const int bb = win >> 10;
  const int wl = win & 1023;
  const int oy = (wl >> 5) * 8, ox = (wl & 31) * 8;
  const int py0 = oy - 2, px0 = ox - 2;

  // ---- Phase 0: zero V kpv-pad gaps, stage x patch (bf16, swz, region B) ----
  {
    int ch = tid >> 3, j = tid & 7;
    *(u64*)(Sm + V_OFF + ch * 336 + 256 + j * 8) = 0ull;
  }
  {
    const float* xb = x + (size_t)bb * 64 * 65536;
    int pix = tid % 144;
    int cq  = tid / 144;
#pragma unroll
    for (int it = 0; it < 5; ++it) {
      if (it < 4 || tid < 256) { // total 2304 units = 144 pix * 16 ch-quads
        int prow = (pix * 171) >> 11;
        int pcol = pix - prow * 12;
        int gy = py0 + prow, gx = px0 + pcol;
        float v0 = 0.f, v1 = 0.f, v2 = 0.f, v3 = 0.f;
        if (((u32)gy < 256u) & ((u32)gx < 256u)) {
          const float* p = xb + (size_t)(cq * 4) * 65536 + gy * 256 + gx;
          v0 = p[0]; v1 = p[65536]; v2 = p[131072]; v3 = p[196608];
        }
        u64 pk = (u64)cvt_pk(v0, v1) | ((u64)cvt_pk(v2, v3) << 32);
        *(u64*)(Sm + ((pix * 128 + cq * 8) ^ ((pix & 7) << 4))) = pk;
      }
      pix += 80; int wr = (pix >= 144); pix -= wr ? 144 : 0; cq += 3 + wr;
    }
  }
  __syncthreads();   // B1: xpatch visible

  // ---- Phase 1: QKV GEMMs into REGISTERS (K and V), Q in-reg ----
  u64 kv[9];
  if (wv < 4) {
    // K channels tile wv: D[m=ch, n=pix]
    const float* wr_ = qkv_w + (size_t)(64 + wv * 16 + l15) * 64;
    bf16x8 a0 = wfrag(wr_ + lg * 8), a1 = wfrag(wr_ + 32 + lg * 8);
    float kb[4];
#pragma unroll
    for (int r = 0; r < 4; ++r) kb[r] = qkv_b[64 + wv * 16 + lg * 4 + r];
#pragma unroll
    for (int nt = 0; nt < 9; ++nt) {
      int pix = nt * 16 + l15;
      int swz = (pix & 7) << 4;
      bf16x8 b0 = *(const bf16x8*)(Sm + ((pix * 128 + lg * 16) ^ swz));
      bf16x8 b1 = *(const bf16x8*)(Sm + ((pix * 128 + 64 + lg * 16) ^ swz));
      f32x4 acc = {0.f, 0.f, 0.f, 0.f};
      acc = MFMA(a0, b0, acc);
      acc = MFMA(a1, b1, acc);
      kv[nt] = (u64)cvt_pk(acc[0] + kb[0], acc[1] + kb[1]) |
               ((u64)cvt_pk(acc[2] + kb[2], acc[3] + kb[3]) << 32);
    }
  } else {
    // V channels tile vt: orientation-2 D[m=pix, n=ch], kpv col packing
    int vt = wv - 4;
    const float* wr_ = qkv_w + (size_t)(128 + vt * 16 + l15) * 64;
    bf16x8 bw0 = wfrag(wr_ + lg * 8), bw1 = wfrag(wr_ + 32 + lg * 8);
    float vb = qkv_b[128 + vt * 16 + l15];
#pragma unroll
    for (int nt = 0; nt < 9; ++nt) {
      int pr = nt * 16 + l15;
      int swz = (pr & 7) << 4;
      bf16x8 a0 = *(const bf16x8*)(Sm + ((pr * 128 + lg * 16) ^ swz));
      bf16x8 a1 = *(const bf16x8*)(Sm + ((pr * 128 + 64 + lg * 16) ^ swz));
      f32x4 acc = {0.f, 0.f, 0.f, 0.f};
      acc = MFMA(a0, bw0, acc);
      acc = MFMA(a1, bw1, acc);
      kv[nt] = (u64)cvt_pk(acc[0] + vb, acc[1] + vb) |
               ((u64)cvt_pk(acc[2] + vb, acc[3] + vb) << 32);
    }
  }
  // Q for this wave's own (h, qh), kept in-reg
  u32 qf[2][2];
  {
    const float* wq = qkv_w + (size_t)(h * 16 + l15) * 64;
    bf16x8 qa0 = wfrag(wq + lg * 8), qa1 = wfrag(wq + 32 + lg * 8);
    float qsb[4];
#pragma unroll
    for (int r = 0; r < 4; ++r) qsb[r] = qkv_b[h * 16 + lg * 4 + r] * SC_LOG2E;
#pragma unroll
    for (int t = 0; t < 2; ++t) {
      int q = (qh * 2 + t) * 16 + l15;
      int pix = ((q >> 3) + 2) * 12 + (q & 7) + 2;
      int swz = (pix & 7) << 4;
      bf16x8 b0 = *(const bf16x8*)(Sm + ((pix * 128 + lg * 16) ^ swz));
      bf16x8 b1 = *(const bf16x8*)(Sm + ((pix * 128 + 64 + lg * 16) ^ swz));
      f32x4 acc = {0.f, 0.f, 0.f, 0.f};
      acc = MFMA(qa0, b0, acc);
      acc = MFMA(qa1, b1, acc);
      qf[t][0] = cvt_pk(acc[0] * SC_LOG2E + qsb[0], acc[1] * SC_LOG2E + qsb[1]);
      qf[t][1] = cvt_pk(acc[2] * SC_LOG2E + qsb[2], acc[3] * SC_LOG2E + qsb[3]);
    }
  }
  __syncthreads();   // B2: all xpatch reads done

  // ---- Phase 1b: spill K/V regs to LDS (K overwrites xpatch region) ----
  if (wv < 4) {
#pragma unroll
    for (int nt = 0; nt < 9; ++nt) {
      int pix = nt * 16 + l15;
      *(u64*)(Sm + ((pix * 128 + wv * 32 + lg * 8) ^ ((pix & 7) << 4))) = kv[nt];
    }
  } else {
    int vt = wv - 4;
#pragma unroll
    for (int nt = 0; nt < 9; ++nt) {
      int colb = (nt >> 1) * 64 + lg * 16 + (nt & 1) * 8;
      *(u64*)(Sm + V_OFF + (vt * 16 + l15) * 336 + colb) = kv[nt];
    }
  }
  __syncthreads();   // B3: K, V visible

  // ---- Phase 2+3: BOTH q-halves fused — shared K/V fragment loads,
  //      two independent MFMA/exp2 chains. No max-sub (range-safe). ----
  const int kcol = h * 32 + lg * 8;
  u64 po[2];
  {
    const bf16x8 bq0 = frag2(qf[0][0], qf[0][1]);
    const bf16x8 bq1 = frag2(qf[1][0], qf[1][1]);
    const float* bp0 = bexp + ((size_t)((h * 4 + qh * 2 + 0) * 9) * 64 + l) * 4;
    const float* bp1 = bexp + ((size_t)((h * 4 + qh * 2 + 1) * 9) * 64 + l) * 4;
    u32 pk0[9][2], pk1[9][2];
    f32x4 sum40 = {0.f, 0.f, 0.f, 0.f}, sum41 = {0.f, 0.f, 0.f, 0.f};
    __builtin_amdgcn_s_setprio(1);
#pragma unroll
    for (int tk = 0; tk < 9; ++tk) {
      int p = tk * 16 + l15;
      u64 kk = *(const u64*)(Sm + ((p * 128 + kcol) ^ ((p & 7) << 4)));
      bf16x8 ak = frag2((u32)kk, (u32)(kk >> 32));
      f32x4 z = {0.f, 0.f, 0.f, 0.f};
      f32x4 s0 = MFMA(ak, bq0, z);
      f32x4 s1 = MFMA(ak, bq1, z);
      s0 += *(const f32x4*)(bp0 + tk * 256);
      s1 += *(const f32x4*)(bp1 + tk * 256);
      f32x4 e0, e1;
#pragma unroll
      for (int r = 0; r < 4; ++r) { e0[r] = EXP2F(s0[r]); e1[r] = EXP2F(s1[r]); }
      sum40 += e0; sum41 += e1;
      pk0[tk][0] = cvt_pk(e0[0], e0[1]); pk0[tk][1] = cvt_pk(e0[2], e0[3]);
      pk1[tk][0] = cvt_pk(e1[0], e1[1]); pk1[tk][1] = cvt_pk(e1[2], e1[3]);
    }
    __builtin_amdgcn_s_setprio(0);
    float sum0 = (sum40[0] + sum40[1]) + (sum40[2] + sum40[3]);
    float sum1 = (sum41[0] + sum41[1]) + (sum41[2] + sum41[3]);
    sum0 += __shfl_xor(sum0, 16); sum1 += __shfl_xor(sum1, 16);
    sum0 += __shfl_xor(sum0, 32); sum1 += __shfl_xor(sum1, 32);
    float rs0 = RCPF(sum0), rs1 = RCPF(sum1);
    f32x4 o0 = {0.f, 0.f, 0.f, 0.f}, o1 = {0.f, 0.f, 0.f, 0.f};
    __builtin_amdgcn_s_setprio(1);
#pragma unroll
    for (int s5 = 0; s5 < 5; ++s5) {
      bf16x8 av = *(const bf16x8*)(Sm + V_OFF + (h * 16 + l15) * 336 + s5 * 64 + lg * 16);
      bf16x8 bpa = (s5 < 4) ? frag4(pk0[2*s5][0], pk0[2*s5][1], pk0[2*s5+1][0], pk0[2*s5+1][1])
                            : frag2(pk0[8][0], pk0[8][1]);
      bf16x8 bpb = (s5 < 4) ? frag4(pk1[2*s5][0], pk1[2*s5][1], pk1[2*s5+1][0], pk1[2*s5+1][1])
                            : frag2(pk1[8][0], pk1[8][1]);
      o0 = MFMA(av, bpa, o0);
      o1 = MFMA(av, bpb, o1);
    }
    __builtin_amdgcn_s_setprio(0);
    po[0] = (u64)cvt_pk(o0[0] * rs0, o0[1] * rs0) |
            ((u64)cvt_pk(o0[2] * rs0, o0[3] * rs0) << 32);
    po[1] = (u64)cvt_pk(o1[0] * rs1, o1[1] * rs1) |
            ((u64)cvt_pk(o1[2] * rs1, o1[3] * rs1) << 32);
  }
  __syncthreads();   // B4: all K reads done, region B reusable

  // ---- Phase 3b: write ATT (both halves) into region B ----
#pragma unroll
  for (int half = 0; half < 2; ++half) {
    int q = (qh * 2 + half) * 16 + l15;
    *(u64*)(Sm + ((q * 128 + kcol) ^ ((q & 7) << 4))) = po[half];
  }
  __syncthreads();   // B5: ATT visible

  // ---- Phase 4: projection, orientation-2: D[m=q, n=och], f32x4 stores ----
  {
    int mt = wv & 3;
    int nb = (wv >> 2) * 2;
    int q = mt * 16 + l15, swz = (q & 7) << 4;
    bf16x8 aa0 = *(const bf16x8*)(Sm + ((q * 128 + lg * 16) ^ swz));
    bf16x8 aa1 = *(const bf16x8*)(Sm + ((q * 128 + 64 + lg * 16) ^ swz));
    int qrow = mt * 16 + lg * 4;
    int gy = oy + (qrow >> 3), gx = ox + (qrow & 7);
#pragma unroll
    for (int nn = 0; nn < 2; ++nn) {
      int ntile = nb + nn;
      const float* pw = proj_w + (size_t)(ntile * 16 + l15) * 64;
      bf16x8 b0 = wfrag(pw + lg * 8), b1 = wfrag(pw + 32 + lg * 8);
      f32x4 acc = {0.f, 0.f, 0.f, 0.f};
      acc = MFMA(aa0, b0, acc);
      acc = MFMA(aa1, b1, acc);
      float pb = proj_b[ntile * 16 + l15];
      f32x4 st = {acc[0] + pb, acc[1] + pb, acc[2] + pb, acc[3] + pb};
      float* yp = out + (((size_t)bb * 64 + ntile * 16 + l15) * 256 + gy) * 256 + gx;
      *(f32x4*)yp = st;
    }
  }
}

extern "C" void kernel_launch(void* const* d_in, const int* in_sizes, int n_in,
                              void* d_out, int out_size, void* d_ws, size_t ws_size,
                              hipStream_t stream) {
  const float* x      = (const float*)d_in[0];
  const float* qkv_w  = (const float*)d_in[1];
  const float* qkv_b  = (const float*)d_in[2];
  const float* rpb    = (const float*)d_in[3];
  const float* proj_w = (const float*)d_in[4];
  const float* proj_b = (const float*)d_in[5];
  float* out  = (float*)d_out;
  float* bexp = (float*)d_ws;   // 147456 bytes

  bias_expand<<<36, 256, 0, stream>>>(rpb, bexp);
  fused_win_attn<<<4096, 512, 0, stream>>>(x, qkv_w, qkv_b, proj_w, proj_b, bexp, out);
}

// Round 16
// 115.908 us; speedup vs baseline: 1.3917x; 1.0134x over previous
//
#include <hip/hip_runtime.h>

typedef unsigned short u16;
typedef unsigned int   u32;
typedef unsigned long long u64;
typedef short bf16x8 __attribute__((ext_vector_type(8)));
typedef float f32x4  __attribute__((ext_vector_type(4)));

#define MFMA(a,b,c) __builtin_amdgcn_mfma_f32_16x16x32_bf16((a),(b),(c),0,0,0)

#if __has_builtin(__builtin_amdgcn_exp2f)
#define EXP2F(x) __builtin_amdgcn_exp2f(x)
#else
#define EXP2F(x) exp2f(x)
#endif
#if __has_builtin(__builtin_amdgcn_rcpf)
#define RCPF(x) __builtin_amdgcn_rcpf(x)
#else
#define RCPF(x) (1.0f/(x))
#endif

__device__ __forceinline__ u32 cvt_pk(float lo, float hi) {
  u32 r;
  asm("v_cvt_pk_bf16_f32 %0, %1, %2" : "=v"(r) : "v"(lo), "v"(hi));
  return r;
}
union FragU { u32 u[4]; bf16x8 v; };
__device__ __forceinline__ bf16x8 frag2(u32 a, u32 b) {
  FragU x; x.u[0] = a; x.u[1] = b; x.u[2] = 0; x.u[3] = 0; return x.v;
}
__device__ __forceinline__ bf16x8 frag4(u32 a, u32 b, u32 c, u32 d) {
  FragU x; x.u[0] = a; x.u[1] = b; x.u[2] = c; x.u[3] = d; return x.v;
}
__device__ __forceinline__ bf16x8 wfrag(const float* p) {
  f32x4 w0 = *(const f32x4*)p;
  f32x4 w1 = *(const f32x4*)(p + 4);
  return frag4(cvt_pk(w0[0], w0[1]), cvt_pk(w0[2], w0[3]),
               cvt_pk(w1[0], w1[1]), cvt_pk(w1[2], w1[3]));
}

// ---------------- LDS layout (bytes) ----------------
// Region B [0, 18432): xpatch [144][64ch] swz (ph0-1) -> K [144][64ch] swz (ph2)
//                      -> ATT [64 q][64 ch] swz (ph3b-4)
// Region A [18432, 39936): V [64 ch][168 kpv-cols] bf16, stride 336 B
constexpr int V_OFF = 18432;
constexpr int SMEM_BYTES = 39936;

constexpr float SC_LOG2E = 0.36067376022224085f;  // 0.25 * log2(e)

// Bias in S^T fragment order: frag f = (h*4 + qt)*9 + tk; lane l; f32x4 over r.
__global__ __launch_bounds__(256)
void bias_expand(const float* __restrict__ rpb, float* __restrict__ bexp)
{
  int gid = blockIdx.x * 256 + threadIdx.x;      // < 9216
  int frag = gid >> 6, l = gid & 63;
  int hh = frag / 36, rem = frag % 36, qt = rem / 9, tk = rem % 9;
  int l15 = l & 15, lg = l >> 4;
  int q = qt * 16 + l15;
  int qy = q >> 3, qx = q & 7;
  f32x4 v;
#pragma unroll
  for (int r = 0; r < 4; ++r) {
    int p = tk * 16 + lg * 4 + r;
    int ky = p / 12, kx = p - ky * 12;
    int idx = (ky - qy + 7) * 19 + (kx - qx + 7);
    v[r] = rpb[idx * 4 + hh] * 1.4426950408889634f;
  }
  *(f32x4*)(bexp + (size_t)gid * 4) = v;
}

__global__ __launch_bounds__(512, 6)
void fused_win_attn(const float* __restrict__ x, const float* __restrict__ qkv_w,
                    const float* __restrict__ qkv_b, const float* __restrict__ proj_w,
                    const float* __restrict__ proj_b, const float* __restrict__ bexp,
                    float* __restrict__ out)
{
  __shared__ __align__(16) char Sm[SMEM_BYTES];
  const int tid = threadIdx.x;
  const int l   = tid & 63;
  const int wv  = tid >> 6;        // wave 0..7
  const int l15 = l & 15;
  const int lg  = l >> 4;          // 0..3
  const int h   = wv >> 1, qh = wv & 1;

  // XCD-aware bijective swizzle (4096 % 8 == 0)
  int bid = blockIdx.x;
  int win = (bid & 7) * 512 + (bid >> 3);
  const int bb = win >> 10;
  const int wl = win & 1023;
  const int oy = (wl >> 5) * 8, ox = (wl & 31) * 8;
  const int py0 = oy - 2, px0 = ox - 2;

  // ---- Phase 0: zero V kpv-pad gaps, stage x patch (bf16, swz, region B).
  //      All 20 global loads issued FIRST (one HBM round-trip), then writes. ----
  {
    int ch = tid >> 3, j = tid & 7;
    *(u64*)(Sm + V_OFF + ch * 336 + 256 + j * 8) = 0ull;
  }
  {
    const float* xb = x + (size_t)bb * 64 * 65536;
    float vbuf[20];
    int offA[5];
    int pix = tid % 144;
    int cq  = tid / 144;
#pragma unroll
    for (int it = 0; it < 5; ++it) {
      if (it < 4 || tid < 256) { // total 2304 units = 144 pix * 16 ch-quads
        int prow = (pix * 171) >> 11;
        int pcol = pix - prow * 12;
        int gy = py0 + prow, gx = px0 + pcol;
        vbuf[it*4+0] = 0.f; vbuf[it*4+1] = 0.f; vbuf[it*4+2] = 0.f; vbuf[it*4+3] = 0.f;
        if (((u32)gy < 256u) & ((u32)gx < 256u)) {
          const float* p = xb + (size_t)(cq * 4) * 65536 + gy * 256 + gx;
          vbuf[it*4+0] = p[0];      vbuf[it*4+1] = p[65536];
          vbuf[it*4+2] = p[131072]; vbuf[it*4+3] = p[196608];
        }
        offA[it] = (pix * 128 + cq * 8) ^ ((pix & 7) << 4);
      }
      pix += 80; int wr = (pix >= 144); pix -= wr ? 144 : 0; cq += 3 + wr;
    }
#pragma unroll
    for (int it = 0; it < 5; ++it) {
      if (it < 4 || tid < 256) {
        u64 pk = (u64)cvt_pk(vbuf[it*4+0], vbuf[it*4+1]) |
                 ((u64)cvt_pk(vbuf[it*4+2], vbuf[it*4+3]) << 32);
        *(u64*)(Sm + offA[it]) = pk;
      }
    }
  }
  __syncthreads();   // B1: xpatch visible

  // ---- Phase 1: QKV GEMMs. K into REGISTERS; V written DIRECTLY to region A
  //      (no alias with xpatch -> safe before B2); Q in-reg. ----
  u64 kv[9];
  if (wv < 4) {
    // K channels tile wv: D[m=ch, n=pix]
    const float* wr_ = qkv_w + (size_t)(64 + wv * 16 + l15) * 64;
    bf16x8 a0 = wfrag(wr_ + lg * 8), a1 = wfrag(wr_ + 32 + lg * 8);
    float kb[4];
#pragma unroll
    for (int r = 0; r < 4; ++r) kb[r] = qkv_b[64 + wv * 16 + lg * 4 + r];
#pragma unroll
    for (int nt = 0; nt < 9; ++nt) {
      int pix = nt * 16 + l15;
      int swz = (pix & 7) << 4;
      bf16x8 b0 = *(const bf16x8*)(Sm + ((pix * 128 + lg * 16) ^ swz));
      bf16x8 b1 = *(const bf16x8*)(Sm + ((pix * 128 + 64 + lg * 16) ^ swz));
      f32x4 acc = {0.f, 0.f, 0.f, 0.f};
      acc = MFMA(a0, b0, acc);
      acc = MFMA(a1, b1, acc);
      kv[nt] = (u64)cvt_pk(acc[0] + kb[0], acc[1] + kb[1]) |
               ((u64)cvt_pk(acc[2] + kb[2], acc[3] + kb[3]) << 32);
    }
  } else {
    // V channels tile vt: orientation-2 D[m=pix, n=ch], kpv col packing;
    // store immediately (region A, ordered after ph0 pad-zero by B1)
    int vt = wv - 4;
    const float* wr_ = qkv_w + (size_t)(128 + vt * 16 + l15) * 64;
    bf16x8 bw0 = wfrag(wr_ + lg * 8), bw1 = wfrag(wr_ + 32 + lg * 8);
    float vb = qkv_b[128 + vt * 16 + l15];
#pragma unroll
    for (int nt = 0; nt < 9; ++nt) {
      int pr = nt * 16 + l15;
      int swz = (pr & 7) << 4;
      bf16x8 a0 = *(const bf16x8*)(Sm + ((pr * 128 + lg * 16) ^ swz));
      bf16x8 a1 = *(const bf16x8*)(Sm + ((pr * 128 + 64 + lg * 16) ^ swz));
      f32x4 acc = {0.f, 0.f, 0.f, 0.f};
      acc = MFMA(a0, bw0, acc);
      acc = MFMA(a1, bw1, acc);
      int colb = (nt >> 1) * 64 + lg * 16 + (nt & 1) * 8;
      u64 pkv = (u64)cvt_pk(acc[0] + vb, acc[1] + vb) |
                ((u64)cvt_pk(acc[2] + vb, acc[3] + vb) << 32);
      *(u64*)(Sm + V_OFF + (vt * 16 + l15) * 336 + colb) = pkv;
    }
  }
  // Q for this wave's own (h, qh), kept in-reg
  u32 qf[2][2];
  {
    const float* wq = qkv_w + (size_t)(h * 16 + l15) * 64;
    bf16x8 qa0 = wfrag(wq + lg * 8), qa1 = wfrag(wq + 32 + lg * 8);
    float qsb[4];
#pragma unroll
    for (int r = 0; r < 4; ++r) qsb[r] = qkv_b[h * 16 + lg * 4 + r] * SC_LOG2E;
#pragma unroll
    for (int t = 0; t < 2; ++t) {
      int q = (qh * 2 + t) * 16 + l15;
      int pix = ((q >> 3) + 2) * 12 + (q & 7) + 2;
      int swz = (pix & 7) << 4;
      bf16x8 b0 = *(const bf16x8*)(Sm + ((pix * 128 + lg * 16) ^ swz));
      bf16x8 b1 = *(const bf16x8*)(Sm + ((pix * 128 + 64 + lg * 16) ^ swz));
      f32x4 acc = {0.f, 0.f, 0.f, 0.f};
      acc = MFMA(qa0, b0, acc);
      acc = MFMA(qa1, b1, acc);
      qf[t][0] = cvt_pk(acc[0] * SC_LOG2E + qsb[0], acc[1] * SC_LOG2E + qsb[1]);
      qf[t][1] = cvt_pk(acc[2] * SC_LOG2E + qsb[2], acc[3] * SC_LOG2E + qsb[3]);
    }
  }
  __syncthreads();   // B2: all xpatch reads done

  // ---- Phase 1b: K waves flush register tiles into region B (xpatch dead) ----
  if (wv < 4) {
#pragma unroll
    for (int nt = 0; nt < 9; ++nt) {
      int pix = nt * 16 + l15;
      *(u64*)(Sm + ((pix * 128 + wv * 32 + lg * 8) ^ ((pix & 7) << 4))) = kv[nt];
    }
  }
  __syncthreads();   // B3: K, V visible

  // ---- Phase 2+3: BOTH q-halves fused — shared K/V fragment loads,
  //      two independent MFMA/exp2 chains. No max-sub (range-safe). ----
  const int kcol = h * 32 + lg * 8;
  u64 po[2];
  {
    const bf16x8 bq0 = frag2(qf[0][0], qf[0][1]);
    const bf16x8 bq1 = frag2(qf[1][0], qf[1][1]);
    const float* bp0 = bexp + ((size_t)((h * 4 + qh * 2 + 0) * 9) * 64 + l) * 4;
    const float* bp1 = bexp + ((size_t)((h * 4 + qh * 2 + 1) * 9) * 64 + l) * 4;
    u32 pk0[9][2], pk1[9][2];
    f32x4 sum40 = {0.f, 0.f, 0.f, 0.f}, sum41 = {0.f, 0.f, 0.f, 0.f};
    __builtin_amdgcn_s_setprio(1);
#pragma unroll
    for (int tk = 0; tk < 9; ++tk) {
      int p = tk * 16 + l15;
      u64 kk = *(const u64*)(Sm + ((p * 128 + kcol) ^ ((p & 7) << 4)));
      bf16x8 ak = frag2((u32)kk, (u32)(kk >> 32));
      f32x4 z = {0.f, 0.f, 0.f, 0.f};
      f32x4 s0 = MFMA(ak, bq0, z);
      f32x4 s1 = MFMA(ak, bq1, z);
      s0 += *(const f32x4*)(bp0 + tk * 256);
      s1 += *(const f32x4*)(bp1 + tk * 256);
      f32x4 e0, e1;
#pragma unroll
      for (int r = 0; r < 4; ++r) { e0[r] = EXP2F(s0[r]); e1[r] = EXP2F(s1[r]); }
      sum40 += e0; sum41 += e1;
      pk0[tk][0] = cvt_pk(e0[0], e0[1]); pk0[tk][1] = cvt_pk(e0[2], e0[3]);
      pk1[tk][0] = cvt_pk(e1[0], e1[1]); pk1[tk][1] = cvt_pk(e1[2], e1[3]);
    }
    __builtin_amdgcn_s_setprio(0);
    float sum0 = (sum40[0] + sum40[1]) + (sum40[2] + sum40[3]);
    float sum1 = (sum41[0] + sum41[1]) + (sum41[2] + sum41[3]);
    sum0 += __shfl_xor(sum0, 16); sum1 += __shfl_xor(sum1, 16);
    sum0 += __shfl_xor(sum0, 32); sum1 += __shfl_xor(sum1, 32);
    float rs0 = RCPF(sum0), rs1 = RCPF(sum1);
    f32x4 o0 = {0.f, 0.f, 0.f, 0.f}, o1 = {0.f, 0.f, 0.f, 0.f};
    __builtin_amdgcn_s_setprio(1);
#pragma unroll
    for (int s5 = 0; s5 < 5; ++s5) {
      bf16x8 av = *(const bf16x8*)(Sm + V_OFF + (h * 16 + l15) * 336 + s5 * 64 + lg * 16);
      bf16x8 bpa = (s5 < 4) ? frag4(pk0[2*s5][0], pk0[2*s5][1], pk0[2*s5+1][0], pk0[2*s5+1][1])
                            : frag2(pk0[8][0], pk0[8][1]);
      bf16x8 bpb = (s5 < 4) ? frag4(pk1[2*s5][0], pk1[2*s5][1], pk1[2*s5+1][0], pk1[2*s5+1][1])
                            : frag2(pk1[8][0], pk1[8][1]);
      o0 = MFMA(av, bpa, o0);
      o1 = MFMA(av, bpb, o1);
    }
    __builtin_amdgcn_s_setprio(0);
    po[0] = (u64)cvt_pk(o0[0] * rs0, o0[1] * rs0) |
            ((u64)cvt_pk(o0[2] * rs0, o0[3] * rs0) << 32);
    po[1] = (u64)cvt_pk(o1[0] * rs1, o1[1] * rs1) |
            ((u64)cvt_pk(o1[2] * rs1, o1[3] * rs1) << 32);
  }
  __syncthreads();   // B4: all K reads done, region B reusable

  // ---- Phase 3b: write ATT (both halves) into region B ----
#pragma unroll
  for (int half = 0; half < 2; ++half) {
    int q = (qh * 2 + half) * 16 + l15;
    *(u64*)(Sm + ((q * 128 + kcol) ^ ((q & 7) << 4))) = po[half];
  }
  __syncthreads();   // B5: ATT visible

  // ---- Phase 4: projection, orientation-2: D[m=q, n=och], f32x4 stores ----
  {
    int mt = wv & 3;
    int nb = (wv >> 2) * 2;
    int q = mt * 16 + l15, swz = (q & 7) << 4;
    bf16x8 aa0 = *(const bf16x8*)(Sm + ((q * 128 + lg * 16) ^ swz));
    bf16x8 aa1 = *(const bf16x8*)(Sm + ((q * 128 + 64 + lg * 16) ^ swz));
    int qrow = mt * 16 + lg * 4;
    int gy = oy + (qrow >> 3), gx = ox + (qrow & 7);
#pragma unroll
    for (int nn = 0; nn < 2; ++nn) {
      int ntile = nb + nn;
      const float* pw = proj_w + (size_t)(ntile * 16 + l15) * 64;
      bf16x8 b0 = wfrag(pw + lg * 8), b1 = wfrag(pw + 32 + lg * 8);
      f32x4 acc = {0.f, 0.f, 0.f, 0.f};
      acc = MFMA(aa0, b0, acc);
      acc = MFMA(aa1, b1, acc);
      float pb = proj_b[ntile * 16 + l15];
      f32x4 st = {acc[0] + pb, acc[1] + pb, acc[2] + pb, acc[3] + pb};
      float* yp = out + (((size_t)bb * 64 + ntile * 16 + l15) * 256 + gy) * 256 + gx;
      *(f32x4*)yp = st;
    }
  }
}

extern "C" void kernel_launch(void* const* d_in, const int* in_sizes, int n_in,
                              void* d_out, int out_size, void* d_ws, size_t ws_size,
                              hipStream_t stream) {
  const float* x      = (const float*)d_in[0];
  const float* qkv_w  = (const float*)d_in[1];
  const float* qkv_b  = (const float*)d_in[2];
  const float* rpb    = (const float*)d_in[3];
  const float* proj_w = (const float*)d_in[4];
  const float* proj_b = (const float*)d_in[5];
  float* out  = (float*)d_out;
  float* bexp = (float*)d_ws;   // 147456 bytes

  bias_expand<<<36, 256, 0, stream>>>(rpb, bexp);
  fused_win_attn<<<4096, 512, 0, stream>>>(x, qkv_w, qkv_b, proj_w, proj_b, bexp, out);
}

// Round 19
// 115.839 us; speedup vs baseline: 1.3925x; 1.0006x over previous
//
#include <hip/hip_runtime.h>

typedef unsigned short u16;
typedef unsigned int   u32;
typedef unsigned long long u64;
typedef short bf16x8 __attribute__((ext_vector_type(8)));
typedef float f32x4  __attribute__((ext_vector_type(4)));

#define MFMA(a,b,c) __builtin_amdgcn_mfma_f32_16x16x32_bf16((a),(b),(c),0,0,0)

#if __has_builtin(__builtin_amdgcn_exp2f)
#define EXP2F(x) __builtin_amdgcn_exp2f(x)
#else
#define EXP2F(x) exp2f(x)
#endif
#if __has_builtin(__builtin_amdgcn_rcpf)
#define RCPF(x) __builtin_amdgcn_rcpf(x)
#else
#define RCPF(x) (1.0f/(x))
#endif

__device__ __forceinline__ u32 cvt_pk(float lo, float hi) {
  u32 r;
  asm("v_cvt_pk_bf16_f32 %0, %1, %2" : "=v"(r) : "v"(lo), "v"(hi));
  return r;
}
union FragU { u32 u[4]; bf16x8 v; };
__device__ __forceinline__ bf16x8 frag2(u32 a, u32 b) {
  FragU x; x.u[0] = a; x.u[1] = b; x.u[2] = 0; x.u[3] = 0; return x.v;
}
__device__ __forceinline__ bf16x8 frag4(u32 a, u32 b, u32 c, u32 d) {
  FragU x; x.u[0] = a; x.u[1] = b; x.u[2] = c; x.u[3] = d; return x.v;
}
__device__ __forceinline__ bf16x8 wfrag(const float* p) {
  f32x4 w0 = *(const f32x4*)p;
  f32x4 w1 = *(const f32x4*)(p + 4);
  return frag4(cvt_pk(w0[0], w0[1]), cvt_pk(w0[2], w0[3]),
               cvt_pk(w1[0], w1[1]), cvt_pk(w1[2], w1[3]));
}

// ---------------- LDS layout (bytes) ----------------
// Region B [0, 18432): xpatch [144][64ch] swz (ph0-1) -> K [144][64ch] swz (ph2)
//                      -> ATT [64 q][64 ch] swz (ph3b-4)
// Region A [18432, 39936): V [64 ch][168 kpv-cols] bf16, stride 336 B
constexpr int V_OFF = 18432;
constexpr int SMEM_BYTES = 39936;

constexpr float SC_LOG2E = 0.36067376022224085f;  // 0.25 * log2(e)

// Bias in S^T fragment order: frag f = (h*4 + qt)*9 + tk; lane l; f32x4 over r.
__global__ __launch_bounds__(256)
void bias_expand(const float* __restrict__ rpb, float* __restrict__ bexp)
{
  int gid = blockIdx.x * 256 + threadIdx.x;      // < 9216
  int frag = gid >> 6, l = gid & 63;
  int hh = frag / 36, rem = frag % 36, qt = rem / 9, tk = rem % 9;
  int l15 = l & 15, lg = l >> 4;
  int q = qt * 16 + l15;
  int qy = q >> 3, qx = q & 7;
  f32x4 v;
#pragma unroll
  for (int r = 0; r < 4; ++r) {
    int p = tk * 16 + lg * 4 + r;
    int ky = p / 12, kx = p - ky * 12;
    int idx = (ky - qy + 7) * 19 + (kx - qx + 7);
    v[r] = rpb[idx * 4 + hh] * 1.4426950408889634f;
  }
  *(f32x4*)(bexp + (size_t)gid * 4) = v;
}

__global__ __launch_bounds__(512, 6)
void fused_win_attn(const float* __restrict__ x, const float* __restrict__ qkv_w,
                    const float* __restrict__ qkv_b, const float* __restrict__ proj_w,
                    const float* __restrict__ proj_b, const float* __restrict__ bexp,
                    float* __restrict__ out)
{
  __shared__ __align__(16) char Sm[SMEM_BYTES];
  const int tid = threadIdx.x;
  const int l   = tid & 63;
  const int wv  = tid >> 6;        // wave 0..7
  const int l15 = l & 15;
  const int lg  = l >> 4;          // 0..3
  const int h   = wv >> 1, qh = wv & 1;

  // XCD-aware bijective swizzle (4096 % 8 == 0)
  int bid = blockIdx.x;
  int win = (bid & 7) * 512 + (bid >> 3);
  const int bb = win >> 10;
  const int wl = win & 1023;
  const int oy = (wl >> 5) * 8, ox = (wl & 31) * 8;
  const int py0 = oy - 2, px0 = ox - 2;

  // ---- Phase 0: zero V kpv-pad gaps, stage x patch (bf16, swz, region B).
  //      All 20 global loads issued FIRST (one HBM round-trip), then writes. ----
  {
    int ch = tid >> 3, j = tid & 7;
    *(u64*)(Sm + V_OFF + ch * 336 + 256 + j * 8) = 0ull;
  }
  {
    const float* xb = x + (size_t)bb * 64 * 65536;
    float vbuf[20];
    int offA[5];
    int pix = tid % 144;
    int cq  = tid / 144;
#pragma unroll
    for (int it = 0; it < 5; ++it) {
      if (it < 4 || tid < 256) { // total 2304 units = 144 pix * 16 ch-quads
        int prow = (pix * 171) >> 11;
        int pcol = pix - prow * 12;
        int gy = py0 + prow, gx = px0 + pcol;
        vbuf[it*4+0] = 0.f; vbuf[it*4+1] = 0.f; vbuf[it*4+2] = 0.f; vbuf[it*4+3] = 0.f;
        if (((u32)gy < 256u) & ((u32)gx < 256u)) {
          const float* p = xb + (size_t)(cq * 4) * 65536 + gy * 256 + gx;
          vbuf[it*4+0] = p[0];      vbuf[it*4+1] = p[65536];
          vbuf[it*4+2] = p[131072]; vbuf[it*4+3] = p[196608];
        }
        offA[it] = (pix * 128 + cq * 8) ^ ((pix & 7) << 4);
      }
      pix += 80; int wr = (pix >= 144); pix -= wr ? 144 : 0; cq += 3 + wr;
    }
#pragma unroll
    for (int it = 0; it < 5; ++it) {
      if (it < 4 || tid < 256) {
        u64 pk = (u64)cvt_pk(vbuf[it*4+0], vbuf[it*4+1]) |
                 ((u64)cvt_pk(vbuf[it*4+2], vbuf[it*4+3]) << 32);
        *(u64*)(Sm + offA[it]) = pk;
      }
    }
  }
  __syncthreads();   // B1: xpatch visible

  // ---- Phase 1: QKV GEMMs. K into REGISTERS; V written DIRECTLY to region A
  //      (no alias with xpatch -> safe before B2); Q in-reg. ----
  u64 kv[9];
  if (wv < 4) {
    // K channels tile wv: D[m=ch, n=pix]
    const float* wr_ = qkv_w + (size_t)(64 + wv * 16 + l15) * 64;
    bf16x8 a0 = wfrag(wr_ + lg * 8), a1 = wfrag(wr_ + 32 + lg * 8);
    float kb[4];
#pragma unroll
    for (int r = 0; r < 4; ++r) kb[r] = qkv_b[64 + wv * 16 + lg * 4 + r];
#pragma unroll
    for (int nt = 0; nt < 9; ++nt) {
      int pix = nt * 16 + l15;
      int swz = (pix & 7) << 4;
      bf16x8 b0 = *(const bf16x8*)(Sm + ((pix * 128 + lg * 16) ^ swz));
      bf16x8 b1 = *(const bf16x8*)(Sm + ((pix * 128 + 64 + lg * 16) ^ swz));
      f32x4 acc = {0.f, 0.f, 0.f, 0.f};
      acc = MFMA(a0, b0, acc);
      acc = MFMA(a1, b1, acc);
      kv[nt] = (u64)cvt_pk(acc[0] + kb[0], acc[1] + kb[1]) |
               ((u64)cvt_pk(acc[2] + kb[2], acc[3] + kb[3]) << 32);
    }
  } else {
    // V channels tile vt: orientation-2 D[m=pix, n=ch], kpv col packing;
    // store immediately (region A, ordered after ph0 pad-zero by B1)
    int vt = wv - 4;
    const float* wr_ = qkv_w + (size_t)(128 + vt * 16 + l15) * 64;
    bf16x8 bw0 = wfrag(wr_ + lg * 8), bw1 = wfrag(wr_ + 32 + lg * 8);
    float vb = qkv_b[128 + vt * 16 + l15];
#pragma unroll
    for (int nt = 0; nt < 9; ++nt) {
      int pr = nt * 16 + l15;
      int swz = (pr & 7) << 4;
      bf16x8 a0 = *(const bf16x8*)(Sm + ((pr * 128 + lg * 16) ^ swz));
      bf16x8 a1 = *(const bf16x8*)(Sm + ((pr * 128 + 64 + lg * 16) ^ swz));
      f32x4 acc = {0.f, 0.f, 0.f, 0.f};
      acc = MFMA(a0, bw0, acc);
      acc = MFMA(a1, bw1, acc);
      int colb = (nt >> 1) * 64 + lg * 16 + (nt & 1) * 8;
      u64 pkv = (u64)cvt_pk(acc[0] + vb, acc[1] + vb) |
                ((u64)cvt_pk(acc[2] + vb, acc[3] + vb) << 32);
      *(u64*)(Sm + V_OFF + (vt * 16 + l15) * 336 + colb) = pkv;
    }
  }
  // Q for this wave's own (h, qh), kept in-reg
  u32 qf[2][2];
  {
    const float* wq = qkv_w + (size_t)(h * 16 + l15) * 64;
    bf16x8 qa0 = wfrag(wq + lg * 8), qa1 = wfrag(wq + 32 + lg * 8);
    float qsb[4];
#pragma unroll
    for (int r = 0; r < 4; ++r) qsb[r] = qkv_b[h * 16 + lg * 4 + r] * SC_LOG2E;
#pragma unroll
    for (int t = 0; t < 2; ++t) {
      int q = (qh * 2 + t) * 16 + l15;
      int pix = ((q >> 3) + 2) * 12 + (q & 7) + 2;
      int swz = (pix & 7) << 4;
      bf16x8 b0 = *(const bf16x8*)(Sm + ((pix * 128 + lg * 16) ^ swz));
      bf16x8 b1 = *(const bf16x8*)(Sm + ((pix * 128 + 64 + lg * 16) ^ swz));
      f32x4 acc = {0.f, 0.f, 0.f, 0.f};
      acc = MFMA(qa0, b0, acc);
      acc = MFMA(qa1, b1, acc);
      qf[t][0] = cvt_pk(acc[0] * SC_LOG2E + qsb[0], acc[1] * SC_LOG2E + qsb[1]);
      qf[t][1] = cvt_pk(acc[2] * SC_LOG2E + qsb[2], acc[3] * SC_LOG2E + qsb[3]);
    }
  }
  __syncthreads();   // B2: all xpatch reads done

  // ---- Phase 1b: K waves flush register tiles into region B (xpatch dead) ----
  if (wv < 4) {
#pragma unroll
    for (int nt = 0; nt < 9; ++nt) {
      int pix = nt * 16 + l15;
      *(u64*)(Sm + ((pix * 128 + wv * 32 + lg * 8) ^ ((pix & 7) << 4))) = kv[nt];
    }
  }
  __syncthreads();   // B3: K, V visible

  // ---- Phase 2+3: BOTH q-halves fused — shared K/V fragment loads,
  //      two independent MFMA/exp2 chains. No max-sub (range-safe). ----
  const int kcol = h * 32 + lg * 8;
  u64 po[2];
  {
    const bf16x8 bq0 = frag2(qf[0][0], qf[0][1]);
    const bf16x8 bq1 = frag2(qf[1][0], qf[1][1]);
    const float* bp0 = bexp + ((size_t)((h * 4 + qh * 2 + 0) * 9) * 64 + l) * 4;
    const float* bp1 = bexp + ((size_t)((h * 4 + qh * 2 + 1) * 9) * 64 + l) * 4;
    u32 pk0[9][2], pk1[9][2];
    f32x4 sum40 = {0.f, 0.f, 0.f, 0.f}, sum41 = {0.f, 0.f, 0.f, 0.f};
    __builtin_amdgcn_s_setprio(1);
#pragma unroll
    for (int tk = 0; tk < 9; ++tk) {
      int p = tk * 16 + l15;
      u64 kk = *(const u64*)(Sm + ((p * 128 + kcol) ^ ((p & 7) << 4)));
      bf16x8 ak = frag2((u32)kk, (u32)(kk >> 32));
      f32x4 z = {0.f, 0.f, 0.f, 0.f};
      f32x4 s0 = MFMA(ak, bq0, z);
      f32x4 s1 = MFMA(ak, bq1, z);
      s0 += *(const f32x4*)(bp0 + tk * 256);
      s1 += *(const f32x4*)(bp1 + tk * 256);
      f32x4 e0, e1;
#pragma unroll
      for (int r = 0; r < 4; ++r) { e0[r] = EXP2F(s0[r]); e1[r] = EXP2F(s1[r]); }
      sum40 += e0; sum41 += e1;
      pk0[tk][0] = cvt_pk(e0[0], e0[1]); pk0[tk][1] = cvt_pk(e0[2], e0[3]);
      pk1[tk][0] = cvt_pk(e1[0], e1[1]); pk1[tk][1] = cvt_pk(e1[2], e1[3]);
    }
    __builtin_amdgcn_s_setprio(0);
    float sum0 = (sum40[0] + sum40[1]) + (sum40[2] + sum40[3]);
    float sum1 = (sum41[0] + sum41[1]) + (sum41[2] + sum41[3]);
    sum0 += __shfl_xor(sum0, 16); sum1 += __shfl_xor(sum1, 16);
    sum0 += __shfl_xor(sum0, 32); sum1 += __shfl_xor(sum1, 32);
    float rs0 = RCPF(sum0), rs1 = RCPF(sum1);
    f32x4 o0 = {0.f, 0.f, 0.f, 0.f}, o1 = {0.f, 0.f, 0.f, 0.f};
    __builtin_amdgcn_s_setprio(1);
#pragma unroll
    for (int s5 = 0; s5 < 5; ++s5) {
      bf16x8 av = *(const bf16x8*)(Sm + V_OFF + (h * 16 + l15) * 336 + s5 * 64 + lg * 16);
      bf16x8 bpa = (s5 < 4) ? frag4(pk0[2*s5][0], pk0[2*s5][1], pk0[2*s5+1][0], pk0[2*s5+1][1])
                            : frag2(pk0[8][0], pk0[8][1]);
      bf16x8 bpb = (s5 < 4) ? frag4(pk1[2*s5][0], pk1[2*s5][1], pk1[2*s5+1][0], pk1[2*s5+1][1])
                            : frag2(pk1[8][0], pk1[8][1]);
      o0 = MFMA(av, bpa, o0);
      o1 = MFMA(av, bpb, o1);
    }
    __builtin_amdgcn_s_setprio(0);
    po[0] = (u64)cvt_pk(o0[0] * rs0, o0[1] * rs0) |
            ((u64)cvt_pk(o0[2] * rs0, o0[3] * rs0) << 32);
    po[1] = (u64)cvt_pk(o1[0] * rs1, o1[1] * rs1) |
            ((u64)cvt_pk(o1[2] * rs1, o1[3] * rs1) << 32);
  }
  __syncthreads();   // B4: all K reads done, region B reusable

  // ---- Phase 3b: write ATT (both halves) into region B ----
#pragma unroll
  for (int half = 0; half < 2; ++half) {
    int q = (qh * 2 + half) * 16 + l15;
    *(u64*)(Sm + ((q * 128 + kcol) ^ ((q & 7) << 4))) = po[half];
  }
  __syncthreads();   // B5: ATT visible

  // ---- Phase 4: projection, orientation-2: D[m=q, n=och], f32x4 stores ----
  {
    int mt = wv & 3;
    int nb = (wv >> 2) * 2;
    int q = mt * 16 + l15, swz = (q & 7) << 4;
    bf16x8 aa0 = *(const bf16x8*)(Sm + ((q * 128 + lg * 16) ^ swz));
    bf16x8 aa1 = *(const bf16x8*)(Sm + ((q * 128 + 64 + lg * 16) ^ swz));
    int qrow = mt * 16 + lg * 4;
    int gy = oy + (qrow >> 3), gx = ox + (qrow & 7);
#pragma unroll
    for (int nn = 0; nn < 2; ++nn) {
      int ntile = nb + nn;
      const float* pw = proj_w + (size_t)(ntile * 16 + l15) * 64;
      bf16x8 b0 = wfrag(pw + lg * 8), b1 = wfrag(pw + 32 + lg * 8);
      f32x4 acc = {0.f, 0.f, 0.f, 0.f};
      acc = MFMA(aa0, b0, acc);
      acc = MFMA(aa1, b1, acc);
      float pb = proj_b[ntile * 16 + l15];
      f32x4 st = {acc[0] + pb, acc[1] + pb, acc[2] + pb, acc[3] + pb};
      float* yp = out + (((size_t)bb * 64 + ntile * 16 + l15) * 256 + gy) * 256 + gx;
      *(f32x4*)yp = st;
    }
  }
}

extern "C" void kernel_launch(void* const* d_in, const int* in_sizes, int n_in,
                              void* d_out, int out_size, void* d_ws, size_t ws_size,
                              hipStream_t stream) {
  const float* x      = (const float*)d_in[0];
  const float* qkv_w  = (const float*)d_in[1];
  const float* qkv_b  = (const float*)d_in[2];
  const float* rpb    = (const float*)d_in[3];
  const float* proj_w = (const float*)d_in[4];
  const float* proj_b = (const float*)d_in[5];
  float* out  = (float*)d_out;
  float* bexp = (float*)d_ws;   // 147456 bytes

  bias_expand<<<36, 256, 0, stream>>>(rpb, bexp);
  fused_win_attn<<<4096, 512, 0, stream>>>(x, qkv_w, qkv_b, proj_w, proj_b, bexp, out);
}

// Round 20
// 115.329 us; speedup vs baseline: 1.3987x; 1.0044x over previous
//
#include <hip/hip_runtime.h>

typedef unsigned short u16;
typedef unsigned int   u32;
typedef unsigned long long u64;
typedef short bf16x8 __attribute__((ext_vector_type(8)));
typedef float f32x4  __attribute__((ext_vector_type(4)));

#define MFMA(a,b,c) __builtin_amdgcn_mfma_f32_16x16x32_bf16((a),(b),(c),0,0,0)

#if __has_builtin(__builtin_amdgcn_exp2f)
#define EXP2F(x) __builtin_amdgcn_exp2f(x)
#else
#define EXP2F(x) exp2f(x)
#endif
#if __has_builtin(__builtin_amdgcn_rcpf)
#define RCPF(x) __builtin_amdgcn_rcpf(x)
#else
#define RCPF(x) (1.0f/(x))
#endif

__device__ __forceinline__ u32 cvt_pk(float lo, float hi) {
  u32 r;
  asm("v_cvt_pk_bf16_f32 %0, %1, %2" : "=v"(r) : "v"(lo), "v"(hi));
  return r;
}
union FragU { u32 u[4]; bf16x8 v; };
__device__ __forceinline__ bf16x8 frag2(u32 a, u32 b) {
  FragU x; x.u[0] = a; x.u[1] = b; x.u[2] = 0; x.u[3] = 0; return x.v;
}
__device__ __forceinline__ bf16x8 frag4(u32 a, u32 b, u32 c, u32 d) {
  FragU x; x.u[0] = a; x.u[1] = b; x.u[2] = c; x.u[3] = d; return x.v;
}
__device__ __forceinline__ bf16x8 wfrag(const float* p) {
  f32x4 w0 = *(const f32x4*)p;
  f32x4 w1 = *(const f32x4*)(p + 4);
  return frag4(cvt_pk(w0[0], w0[1]), cvt_pk(w0[2], w0[3]),
               cvt_pk(w1[0], w1[1]), cvt_pk(w1[2], w1[3]));
}

// ---------------- LDS layout (bytes) ----------------
// Region B [0, 18432): xpatch [144][64ch] swz (ph0-1) -> K [144][64ch] swz (ph2)
//                      -> ATT [64 q][64 ch] swz (ph3b-4)
// Region A [18432, 39936): V [64 ch][168 kpv-cols] bf16, stride 336 B
constexpr int V_OFF = 18432;
constexpr int SMEM_BYTES = 39936;

constexpr float SC_LOG2E = 0.36067376022224085f;  // 0.25 * log2(e)

// Bias in S^T fragment order: frag f = (h*4 + qt)*9 + tk; lane l; f32x4 over r.
__global__ __launch_bounds__(256)
void bias_expand(const float* __restrict__ rpb, float* __restrict__ bexp)
{
  int gid = blockIdx.x * 256 + threadIdx.x;      // < 9216
  int frag = gid >> 6, l = gid & 63;
  int hh = frag / 36, rem = frag % 36, qt = rem / 9, tk = rem % 9;
  int l15 = l & 15, lg = l >> 4;
  int q = qt * 16 + l15;
  int qy = q >> 3, qx = q & 7;
  f32x4 v;
#pragma unroll
  for (int r = 0; r < 4; ++r) {
    int p = tk * 16 + lg * 4 + r;
    int ky = p / 12, kx = p - ky * 12;
    int idx = (ky - qy + 7) * 19 + (kx - qx + 7);
    v[r] = rpb[idx * 4 + hh] * 1.4426950408889634f;
  }
  *(f32x4*)(bexp + (size_t)gid * 4) = v;
}

__global__ __launch_bounds__(512, 6)
void fused_win_attn(const float* __restrict__ x, const float* __restrict__ qkv_w,
                    const float* __restrict__ qkv_b, const float* __restrict__ proj_w,
                    const float* __restrict__ proj_b, const float* __restrict__ bexp,
                    float* __restrict__ out)
{
  __shared__ __align__(16) char Sm[SMEM_BYTES];
  const int tid = threadIdx.x;
  const int l   = tid & 63;
  const int wv  = tid >> 6;        // wave 0..7
  const int l15 = l & 15;
  const int lg  = l >> 4;          // 0..3
  const int h   = wv >> 1, qh = wv & 1;

  // XCD-aware bijective swizzle (4096 % 8 == 0)
  int bid = blockIdx.x;
  int win = (bid & 7) * 512 + (bid >> 3);
  const int bb = win >> 10;
  const int wl = win & 1023;
  const int oy = (wl >> 5) * 8, ox = (wl & 31) * 8;
  const int py0 = oy - 2, px0 = ox - 2;

  // ---- Phase 0: zero V kpv-pad gaps, stage x patch (bf16, swz, region B).
  //      All 20 global loads issued FIRST (one HBM round-trip), then writes. ----
  {
    int ch = tid >> 3, j = tid & 7;
    *(u64*)(Sm + V_OFF + ch * 336 + 256 + j * 8) = 0ull;
  }
  {
    const float* xb = x + (size_t)bb * 64 * 65536;
    float vbuf[20];
    int offA[5];
    int pix = tid % 144;
    int cq  = tid / 144;
#pragma unroll
    for (int it = 0; it < 5; ++it) {
      if (it < 4 || tid < 256) { // total 2304 units = 144 pix * 16 ch-quads
        int prow = (pix * 171) >> 11;
        int pcol = pix - prow * 12;
        int gy = py0 + prow, gx = px0 + pcol;
        vbuf[it*4+0] = 0.f; vbuf[it*4+1] = 0.f; vbuf[it*4+2] = 0.f; vbuf[it*4+3] = 0.f;
        if (((u32)gy < 256u) & ((u32)gx < 256u)) {
          const float* p = xb + (size_t)(cq * 4) * 65536 + gy * 256 + gx;
          vbuf[it*4+0] = p[0];      vbuf[it*4+1] = p[65536];
          vbuf[it*4+2] = p[131072]; vbuf[it*4+3] = p[196608];
        }
        offA[it] = (pix * 128 + cq * 8) ^ ((pix & 7) << 4);
      }
      pix += 80; int wr = (pix >= 144); pix -= wr ? 144 : 0; cq += 3 + wr;
    }
#pragma unroll
    for (int it = 0; it < 5; ++it) {
      if (it < 4 || tid < 256) {
        u64 pk = (u64)cvt_pk(vbuf[it*4+0], vbuf[it*4+1]) |
                 ((u64)cvt_pk(vbuf[it*4+2], vbuf[it*4+3]) << 32);
        *(u64*)(Sm + offA[it]) = pk;
      }
    }
  }
  __syncthreads();   // B1: xpatch visible

  // ---- Phase 1: QKV GEMMs. K into REGISTERS; V written DIRECTLY to region A
  //      (no alias with xpatch -> safe before B2); Q in-reg. ----
  u64 kv[9];
  if (wv < 4) {
    // K channels tile wv: D[m=ch, n=pix]
    const float* wr_ = qkv_w + (size_t)(64 + wv * 16 + l15) * 64;
    bf16x8 a0 = wfrag(wr_ + lg * 8), a1 = wfrag(wr_ + 32 + lg * 8);
    float kb[4];
#pragma unroll
    for (int r = 0; r < 4; ++r) kb[r] = qkv_b[64 + wv * 16 + lg * 4 + r];
#pragma unroll
    for (int nt = 0; nt < 9; ++nt) {
      int pix = nt * 16 + l15;
      int swz = (pix & 7) << 4;
      bf16x8 b0 = *(const bf16x8*)(Sm + ((pix * 128 + lg * 16) ^ swz));
      bf16x8 b1 = *(const bf16x8*)(Sm + ((pix * 128 + 64 + lg * 16) ^ swz));
      f32x4 acc = {0.f, 0.f, 0.f, 0.f};
      acc = MFMA(a0, b0, acc);
      acc = MFMA(a1, b1, acc);
      kv[nt] = (u64)cvt_pk(acc[0] + kb[0], acc[1] + kb[1]) |
               ((u64)cvt_pk(acc[2] + kb[2], acc[3] + kb[3]) << 32);
    }
  } else {
    // V channels tile vt: orientation-2 D[m=pix, n=ch], kpv col packing;
    // store immediately (region A, ordered after ph0 pad-zero by B1)
    int vt = wv - 4;
    const float* wr_ = qkv_w + (size_t)(128 + vt * 16 + l15) * 64;
    bf16x8 bw0 = wfrag(wr_ + lg * 8), bw1 = wfrag(wr_ + 32 + lg * 8);
    float vb = qkv_b[128 + vt * 16 + l15];
#pragma unroll
    for (int nt = 0; nt < 9; ++nt) {
      int pr = nt * 16 + l15;
      int swz = (pr & 7) << 4;
      bf16x8 a0 = *(const bf16x8*)(Sm + ((pr * 128 + lg * 16) ^ swz));
      bf16x8 a1 = *(const bf16x8*)(Sm + ((pr * 128 + 64 + lg * 16) ^ swz));
      f32x4 acc = {0.f, 0.f, 0.f, 0.f};
      acc = MFMA(a0, bw0, acc);
      acc = MFMA(a1, bw1, acc);
      int colb = (nt >> 1) * 64 + lg * 16 + (nt & 1) * 8;
      u64 pkv = (u64)cvt_pk(acc[0] + vb, acc[1] + vb) |
                ((u64)cvt_pk(acc[2] + vb, acc[3] + vb) << 32);
      *(u64*)(Sm + V_OFF + (vt * 16 + l15) * 336 + colb) = pkv;
    }
  }
  // Q for this wave's own (h, qh), kept in-reg
  u32 qf[2][2];
  {
    const float* wq = qkv_w + (size_t)(h * 16 + l15) * 64;
    bf16x8 qa0 = wfrag(wq + lg * 8), qa1 = wfrag(wq + 32 + lg * 8);
    float qsb[4];
#pragma unroll
    for (int r = 0; r < 4; ++r) qsb[r] = qkv_b[h * 16 + lg * 4 + r] * SC_LOG2E;
#pragma unroll
    for (int t = 0; t < 2; ++t) {
      int q = (qh * 2 + t) * 16 + l15;
      int pix = ((q >> 3) + 2) * 12 + (q & 7) + 2;
      int swz = (pix & 7) << 4;
      bf16x8 b0 = *(const bf16x8*)(Sm + ((pix * 128 + lg * 16) ^ swz));
      bf16x8 b1 = *(const bf16x8*)(Sm + ((pix * 128 + 64 + lg * 16) ^ swz));
      f32x4 acc = {0.f, 0.f, 0.f, 0.f};
      acc = MFMA(qa0, b0, acc);
      acc = MFMA(qa1, b1, acc);
      qf[t][0] = cvt_pk(acc[0] * SC_LOG2E + qsb[0], acc[1] * SC_LOG2E + qsb[1]);
      qf[t][1] = cvt_pk(acc[2] * SC_LOG2E + qsb[2], acc[3] * SC_LOG2E + qsb[3]);
    }
  }
  __syncthreads();   // B2: all xpatch reads done

  // ---- Phase 1b: K waves flush register tiles into region B (xpatch dead) ----
  if (wv < 4) {
#pragma unroll
    for (int nt = 0; nt < 9; ++nt) {
      int pix = nt * 16 + l15;
      *(u64*)(Sm + ((pix * 128 + wv * 32 + lg * 8) ^ ((pix & 7) << 4))) = kv[nt];
    }
  }
  __syncthreads();   // B3: K, V visible

  // ---- Phase 2+3: BOTH q-halves fused — shared K/V fragment loads,
  //      two independent MFMA/exp2 chains. No max-sub (range-safe).
  //      (setprio removed: lockstep barrier-synced waves -> T5 regime absent) ----
  const int kcol = h * 32 + lg * 8;
  u64 po[2];
  {
    const bf16x8 bq0 = frag2(qf[0][0], qf[0][1]);
    const bf16x8 bq1 = frag2(qf[1][0], qf[1][1]);
    const float* bp0 = bexp + ((size_t)((h * 4 + qh * 2 + 0) * 9) * 64 + l) * 4;
    const float* bp1 = bexp + ((size_t)((h * 4 + qh * 2 + 1) * 9) * 64 + l) * 4;
    u32 pk0[9][2], pk1[9][2];
    f32x4 sum40 = {0.f, 0.f, 0.f, 0.f}, sum41 = {0.f, 0.f, 0.f, 0.f};
#pragma unroll
    for (int tk = 0; tk < 9; ++tk) {
      int p = tk * 16 + l15;
      u64 kk = *(const u64*)(Sm + ((p * 128 + kcol) ^ ((p & 7) << 4)));
      bf16x8 ak = frag2((u32)kk, (u32)(kk >> 32));
      f32x4 z = {0.f, 0.f, 0.f, 0.f};
      f32x4 s0 = MFMA(ak, bq0, z);
      f32x4 s1 = MFMA(ak, bq1, z);
      s0 += *(const f32x4*)(bp0 + tk * 256);
      s1 += *(const f32x4*)(bp1 + tk * 256);
      f32x4 e0, e1;
#pragma unroll
      for (int r = 0; r < 4; ++r) { e0[r] = EXP2F(s0[r]); e1[r] = EXP2F(s1[r]); }
      sum40 += e0; sum41 += e1;
      pk0[tk][0] = cvt_pk(e0[0], e0[1]); pk0[tk][1] = cvt_pk(e0[2], e0[3]);
      pk1[tk][0] = cvt_pk(e1[0], e1[1]); pk1[tk][1] = cvt_pk(e1[2], e1[3]);
    }
    float sum0 = (sum40[0] + sum40[1]) + (sum40[2] + sum40[3]);
    float sum1 = (sum41[0] + sum41[1]) + (sum41[2] + sum41[3]);
    sum0 += __shfl_xor(sum0, 16); sum1 += __shfl_xor(sum1, 16);
    sum0 += __shfl_xor(sum0, 32); sum1 += __shfl_xor(sum1, 32);
    float rs0 = RCPF(sum0), rs1 = RCPF(sum1);
    f32x4 o0 = {0.f, 0.f, 0.f, 0.f}, o1 = {0.f, 0.f, 0.f, 0.f};
#pragma unroll
    for (int s5 = 0; s5 < 5; ++s5) {
      bf16x8 av = *(const bf16x8*)(Sm + V_OFF + (h * 16 + l15) * 336 + s5 * 64 + lg * 16);
      bf16x8 bpa = (s5 < 4) ? frag4(pk0[2*s5][0], pk0[2*s5][1], pk0[2*s5+1][0], pk0[2*s5+1][1])
                            : frag2(pk0[8][0], pk0[8][1]);
      bf16x8 bpb = (s5 < 4) ? frag4(pk1[2*s5][0], pk1[2*s5][1], pk1[2*s5+1][0], pk1[2*s5+1][1])
                            : frag2(pk1[8][0], pk1[8][1]);
      o0 = MFMA(av, bpa, o0);
      o1 = MFMA(av, bpb, o1);
    }
    po[0] = (u64)cvt_pk(o0[0] * rs0, o0[1] * rs0) |
            ((u64)cvt_pk(o0[2] * rs0, o0[3] * rs0) << 32);
    po[1] = (u64)cvt_pk(o1[0] * rs1, o1[1] * rs1) |
            ((u64)cvt_pk(o1[2] * rs1, o1[3] * rs1) << 32);
  }
  __syncthreads();   // B4: all K reads done, region B reusable

  // ---- Phase 3b: write ATT (both halves) into region B ----
#pragma unroll
  for (int half = 0; half < 2; ++half) {
    int q = (qh * 2 + half) * 16 + l15;
    *(u64*)(Sm + ((q * 128 + kcol) ^ ((q & 7) << 4))) = po[half];
  }
  __syncthreads();   // B5: ATT visible

  // ---- Phase 4: projection, orientation-2: D[m=q, n=och], f32x4 stores ----
  {
    int mt = wv & 3;
    int nb = (wv >> 2) * 2;
    int q = mt * 16 + l15, swz = (q & 7) << 4;
    bf16x8 aa0 = *(const bf16x8*)(Sm + ((q * 128 + lg * 16) ^ swz));
    bf16x8 aa1 = *(const bf16x8*)(Sm + ((q * 128 + 64 + lg * 16) ^ swz));
    int qrow = mt * 16 + lg * 4;
    int gy = oy + (qrow >> 3), gx = ox + (qrow & 7);
#pragma unroll
    for (int nn = 0; nn < 2; ++nn) {
      int ntile = nb + nn;
      const float* pw = proj_w + (size_t)(ntile * 16 + l15) * 64;
      bf16x8 b0 = wfrag(pw + lg * 8), b1 = wfrag(pw + 32 + lg * 8);
      f32x4 acc = {0.f, 0.f, 0.f, 0.f};
      acc = MFMA(aa0, b0, acc);
      acc = MFMA(aa1, b1, acc);
      float pb = proj_b[ntile * 16 + l15];
      f32x4 st = {acc[0] + pb, acc[1] + pb, acc[2] + pb, acc[3] + pb};
      float* yp = out + (((size_t)bb * 64 + ntile * 16 + l15) * 256 + gy) * 256 + gx;
      *(f32x4*)yp = st;
    }
  }
}

extern "C" void kernel_launch(void* const* d_in, const int* in_sizes, int n_in,
                              void* d_out, int out_size, void* d_ws, size_t ws_size,
                              hipStream_t stream) {
  const float* x      = (const float*)d_in[0];
  const float* qkv_w  = (const float*)d_in[1];
  const float* qkv_b  = (const float*)d_in[2];
  const float* rpb    = (const float*)d_in[3];
  const float* proj_w = (const float*)d_in[4];
  const float* proj_b = (const float*)d_in[5];
  float* out  = (float*)d_out;
  float* bexp = (float*)d_ws;   // 147456 bytes

  bias_expand<<<36, 256, 0, stream>>>(rpb, bexp);
  fused_win_attn<<<4096, 512, 0, stream>>>(x, qkv_w, qkv_b, proj_w, proj_b, bexp, out);
}